// Round 5
// baseline (847.378 us; speedup 1.0000x reference)
//
#include <hip/hip_runtime.h>
#include <cstdint>

namespace {
constexpr int kN = 50000;          // nodes per encoder
constexpr int kE = 200000;         // directed edges per encoder (pre self-loop)
constexpr int kE2 = kE + kN;       // with self loops (per encoder)
constexpr int kG = 256;            // graphs per encoder
constexpr float kNegSlope = 0.2f;
}

using half8   = __attribute__((ext_vector_type(8))) _Float16;
using floatx4 = __attribute__((ext_vector_type(4))) float;

__device__ __forceinline__ void gld_lds16(const void* g, void* l) {
  __builtin_amdgcn_global_load_lds(
      (const __attribute__((address_space(1))) unsigned int*)g,
      (__attribute__((address_space(3))) unsigned int*)l, 16, 0, 0);
}

// fast exp: e^x = 2^(x*log2(e)) via hardware v_exp_f32 (no libm call)
__device__ __forceinline__ float fexp(float x) {
  return __builtin_amdgcn_exp2f(x * 1.44269504088896f);
}

// ---------------- fp16 MFMA GEMM: C[M,N] = A[M,K] @ B[K,N] -----------
// R15 ring schedule (T3+T4+T5): 4-slot LDS ring, prefetch distance 3,
// counted vmcnt (never 0 in loop), setprio around MFMA clusters.
// R17: epilogue reverted to plain C-write. R16's fused attention dots
// (shfl reduce + atomics) cost +85us in atomic WRITE traffic; the dots
// now come for free via linearity: asrc = A @ (W @ a), computed where
// A is already in registers (prep2 / previous layer's agg epilogue).
template <int OUTF16, int BN, int CT>
__global__ __launch_bounds__(512, 2) void gemm_ring(
    const _Float16* __restrict__ A, const _Float16* __restrict__ B,
    void* __restrict__ Cv, int M, int N, int K) {
  constexpr int ASL = 1024;                // A slots/tile (256 rows x 32k x 2B /16)
  constexpr int BSL = BN * 4;              // B slots/tile (1024 or 512)
  constexpr int SLOT = (ASL + BSL) * 16;   // 32KB or 24KB
  constexpr int LPT = (ASL + BSL) / 512;   // loads/thread/tile: 4 or 3
  constexpr int WN = (BN == 256) ? 4 : 2;  // waves along N
  constexpr int WM = 8 / WN;
  constexpr int WTM = 256 / WM;            // 128 or 64
  constexpr int WTN = BN / WN;             // 64
  constexpr int MI = WTM / 16;             // 8 or 4
  constexpr int NI = WTN / 16;             // 4
  __shared__ alignas(16) char smem[4 * SLOT];  // 128KB or 96KB ring
  const int t = threadIdx.x;
  const int w = t >> 6, l = t & 63;
  const int x = blockIdx.x & 7, s = blockIdx.x >> 3;
  const int col = (CT == 1) ? 0 : (s & (CT - 1));
  const int rt = ((CT == 1) ? s : (s >> 1)) * 8 + x;
  const int bm = rt * 256;
  const int bn = col * BN;
  if (bm >= M) return;  // padded row-tiles: whole block exits (no barrier)
  const int wr = w / WN, wc = w % WN;
  const int quad = l >> 4, lrow = l & 15;

  floatx4 acc[MI][NI];
#pragma unroll
  for (int mi = 0; mi < MI; ++mi)
#pragma unroll
    for (int ni = 0; ni < NI; ++ni) acc[mi][ni] = (floatx4){0.f, 0.f, 0.f, 0.f};

  // stage tile kt's A-part (2 loads) / B-part (LPT-2 loads) into ring slot
  auto stageA = [&](int kt) {
    char* buf = smem + (size_t)(kt & 3) * SLOT;
    int k0 = kt * 32;
    k0 = (k0 > K - 32) ? (K - 32) : k0;  // clamp: beyond-NT garbage stays in-bounds
#pragma unroll
    for (int i = 0; i < 2; ++i) {
      const int sl = i * 512 + t;
      const int row = ((sl >> 6) << 4) + (sl & 15);
      const int q = (sl >> 4) & 3;
      int ga = bm + row;
      ga = (ga < M) ? ga : (M - 1);      // clamp: keep lanes active
      gld_lds16(A + (size_t)ga * K + k0 + q * 8, buf + sl * 16);
    }
  };
  auto stageB = [&](int kt) {
    char* buf = smem + (size_t)(kt & 3) * SLOT + ASL * 16;
    int k0 = kt * 32;
    k0 = (k0 > K - 32) ? (K - 32) : k0;
#pragma unroll
    for (int i = 0; i < LPT - 2; ++i) {
      const int sl = i * 512 + t;
      const int row = ((sl >> 6) << 4) + (sl & 15);
      const int q = (sl >> 4) & 3;
      gld_lds16(B + (size_t)(bn + row) * K + k0 + q * 8, buf + sl * 16);
    }
  };

  // prologue: tiles 0,1,2 in flight (3*LPT loads)
  stageA(0); stageB(0);
  stageA(1); stageB(1);
  stageA(2); stageB(2);

  const int NT = K >> 5;
  for (int kt = 0; kt < NT; ++kt) {
    char* bufc = smem + (size_t)(kt & 3) * SLOT;
    // ---- phase A ----
    stageA(kt + 3);  // 2 loads of tile kt+3 (slot of finished tile kt-1)
    if constexpr (BN == 256)
      asm volatile("s_waitcnt vmcnt(10)" ::: "memory");  // tile kt's 4 landed
    else
      asm volatile("s_waitcnt vmcnt(8)" ::: "memory");   // tile kt's 3 landed
    __builtin_amdgcn_s_barrier();        // all waves: slot[kt&3] ready
    asm volatile("" ::: "memory");
    half8 fa[MI], fb[NI];
#pragma unroll
    for (int ni = 0; ni < NI; ++ni)
      fb[ni] = *(const half8*)(bufc + ASL * 16 + ((wc * NI + ni) << 10) + l * 16);
#pragma unroll
    for (int mi = 0; mi < MI / 2; ++mi)
      fa[mi] = *(const half8*)(bufc + ((wr * MI + mi) << 10) + l * 16);
    __builtin_amdgcn_s_setprio(1);
#pragma unroll
    for (int mi = 0; mi < MI / 2; ++mi)
#pragma unroll
      for (int ni = 0; ni < NI; ++ni)
        acc[mi][ni] = __builtin_amdgcn_mfma_f32_16x16x32_f16(
            fa[mi], fb[ni], acc[mi][ni], 0, 0, 0);
    __builtin_amdgcn_s_setprio(0);
    // ---- phase B ----
    stageB(kt + 3);  // remaining loads of tile kt+3
#pragma unroll
    for (int mi = MI / 2; mi < MI; ++mi)
      fa[mi] = *(const half8*)(bufc + ((wr * MI + mi) << 10) + l * 16);
    __builtin_amdgcn_s_setprio(1);
#pragma unroll
    for (int mi = MI / 2; mi < MI; ++mi)
#pragma unroll
      for (int ni = 0; ni < NI; ++ni)
        acc[mi][ni] = __builtin_amdgcn_mfma_f32_16x16x32_f16(
            fa[mi], fb[ni], acc[mi][ni], 0, 0, 0);
    __builtin_amdgcn_s_setprio(0);
    asm volatile("" ::: "memory");
    __builtin_amdgcn_s_barrier();        // slot[kt&3] reusable for kt+4
  }
  asm volatile("s_waitcnt vmcnt(0)" ::: "memory");  // drain garbage prefetches
  // epilogue: C/D layout col=lane&15, row=quad*4+reg
  const int colbase = bn + wc * WTN + lrow;
#pragma unroll
  for (int mi = 0; mi < MI; ++mi) {
    const int rbase = bm + wr * WTM + mi * 16 + quad * 4;
#pragma unroll
    for (int r = 0; r < 4; ++r) {
      const int grow = rbase + r;
      if (grow < M) {
        if constexpr (OUTF16) {
          _Float16* C = (_Float16*)Cv;
#pragma unroll
          for (int ni = 0; ni < NI; ++ni)
            C[(size_t)grow * N + colbase + ni * 16] = (_Float16)acc[mi][ni][r];
        } else {
          float* C = (float*)Cv;
#pragma unroll
          for (int ni = 0; ni < NI; ++ni)
            C[(size_t)grow * N + colbase + ni * 16] = acc[mi][ni][r];
        }
      }
    }
  }
}

// --- weight transposes + f16 casts + wa = W @ a projections -----------
// wa1 [64][8], wa2 [512][8] (j<4: src head j; j>=4: dst head j-4),
// wa3 [512][2] (0:src, 1:dst). asrc_l = A_l @ wa_l by linearity.
__global__ void wt_split_all(const float* __restrict__ W1, _Float16* Th1,
                             const float* __restrict__ W2, _Float16* Th2,
                             const float* __restrict__ W3, _Float16* Th3,
                             const float* __restrict__ as1, const float* __restrict__ ad1,
                             const float* __restrict__ as2, const float* __restrict__ ad2,
                             const float* __restrict__ as3, const float* __restrict__ ad3,
                             float* __restrict__ wa1, float* __restrict__ wa2,
                             float* __restrict__ wa3) {
  int idx = blockIdx.x * blockDim.x + threadIdx.x;
  const int wtot = 64 * 512 + 512 * 512 + 512 * 128;
  if (idx < wtot) {
    const float* W;
    _Float16* Th;
    int K, N;
    if (idx < 64 * 512) {
      W = W1; Th = Th1; K = 64; N = 512;
    } else if (idx < 64 * 512 + 512 * 512) {
      idx -= 64 * 512;
      W = W2; Th = Th2; K = 512; N = 512;
    } else {
      idx -= 64 * 512 + 512 * 512;
      W = W3; Th = Th3; K = 512; N = 128;
    }
    const int k = idx / N;
    const int n = idx - k * N;
    Th[n * K + k] = (_Float16)W[idx];
    return;
  }
  int e = idx - wtot;
  if (e < 64 * 8) {  // wa1[k][j] = sum_c W1[k, hd*128+c] * a1[hd, c]
    const int k = e >> 3, j = e & 7, hd = j & 3;
    const float* a = (j < 4) ? as1 : ad1;
    float sum = 0.f;
    for (int c = 0; c < 128; ++c)
      sum = fmaf(W1[k * 512 + hd * 128 + c], a[hd * 128 + c], sum);
    wa1[k * 8 + j] = sum;
  } else if ((e -= 64 * 8) < 512 * 8) {  // wa2
    const int k = e >> 3, j = e & 7, hd = j & 3;
    const float* a = (j < 4) ? as2 : ad2;
    float sum = 0.f;
    for (int c = 0; c < 128; ++c)
      sum = fmaf(W2[k * 512 + hd * 128 + c], a[hd * 128 + c], sum);
    wa2[k * 8 + j] = sum;
  } else if ((e -= 512 * 8) < 512 * 2) {  // wa3 (H=1)
    const int k = e >> 1, j = e & 1;
    const float* a = j ? ad3 : as3;
    float sum = 0.f;
    for (int c = 0; c < 128; ++c) sum = fmaf(W3[k * 128 + c], a[c], sum);
    wa3[k * 2 + j] = sum;
  }
}

// --- prep: x casts + layer-1 node scores + cnt=1 + total=0 ------------
// One wave per node (lane = feature k). Scores: p[j] = sum_k x[k]*wa1[k][j]
// via 8 FMA/lane + 48 shfl once per node — no extra memory pass.
__global__ void prep2(const float* __restrict__ x0, const float* __restrict__ x1,
                      _Float16* __restrict__ Xh, int* __restrict__ cnt,
                      int* __restrict__ total, const float* __restrict__ wa1,
                      float* __restrict__ aS1, float* __restrict__ aD1) {
  const int gtid = blockIdx.x * blockDim.x + threadIdx.x;
  const int node = gtid >> 6;
  const int lane = threadIdx.x & 63;
  if (node >= 2 * kN) return;
  const float xv = (node < kN) ? x0[(size_t)node * 64 + lane]
                               : x1[(size_t)(node - kN) * 64 + lane];
  Xh[(size_t)node * 64 + lane] = (_Float16)xv;
  float w8[8];
  *(float4*)w8 = *(const float4*)(wa1 + lane * 8);
  *(float4*)(w8 + 4) = *(const float4*)(wa1 + lane * 8 + 4);
  float p[8];
#pragma unroll
  for (int j = 0; j < 8; ++j) p[j] = xv * w8[j];
#pragma unroll
  for (int off = 1; off < 64; off <<= 1)
#pragma unroll
    for (int j = 0; j < 8; ++j) p[j] += __shfl_xor(p[j], off);
  if (lane == 0) {
#pragma unroll
    for (int hd = 0; hd < 4; ++hd) {
      aS1[node * 4 + hd] = p[hd];
      aD1[node * 4 + hd] = p[4 + hd];
    }
    cnt[node] = 1;  // the self loop
    if (node == 0) *total = 0;
  }
}
// ------- single-encoder prep (fallback path) --------------------------
__global__ void prep(const float* __restrict__ X, _Float16* __restrict__ Xh,
                     int* __restrict__ cnt, int* __restrict__ total,
                     const float* __restrict__ wa1, float* __restrict__ aS1,
                     float* __restrict__ aD1, int n) {
  const int gtid = blockIdx.x * blockDim.x + threadIdx.x;
  const int node = gtid >> 6;
  const int lane = threadIdx.x & 63;
  if (node >= n) return;
  const float xv = X[(size_t)node * 64 + lane];
  Xh[(size_t)node * 64 + lane] = (_Float16)xv;
  float w8[8];
  *(float4*)w8 = *(const float4*)(wa1 + lane * 8);
  *(float4*)(w8 + 4) = *(const float4*)(wa1 + lane * 8 + 4);
  float p[8];
#pragma unroll
  for (int j = 0; j < 8; ++j) p[j] = xv * w8[j];
#pragma unroll
  for (int off = 1; off < 64; off <<= 1)
#pragma unroll
    for (int j = 0; j < 8; ++j) p[j] += __shfl_xor(p[j], off);
  if (lane == 0) {
#pragma unroll
    for (int hd = 0; hd < 4; ++hd) {
      aS1[node * 4 + hd] = p[hd];
      aD1[node * 4 + hd] = p[4 + hd];
    }
    cnt[node] = 1;
    if (node == 0) *total = 0;
  }
}

// ---------------- CSR (by dst) build ----------------------------------
__global__ void count_edges2(const int* __restrict__ d0, const int* __restrict__ d1,
                             int* __restrict__ cnt) {
  const int i = blockIdx.x * blockDim.x + threadIdx.x;
  if (i < kE) atomicAdd(&cnt[d0[i]], 1);
  else if (i < 2 * kE) atomicAdd(&cnt[d1[i - kE] + kN], 1);
}
__global__ void fill_edges2(const int* __restrict__ s0, const int* __restrict__ d0,
                            const int* __restrict__ s1, const int* __restrict__ d1,
                            int* __restrict__ cursor, int* __restrict__ csr) {
  const int i = blockIdx.x * blockDim.x + threadIdx.x;
  if (i < kE) {
    const int p = atomicAdd(&cursor[d0[i]], 1);
    csr[p] = s0[i];
  } else if (i < 2 * kE) {
    const int j = i - kE;
    const int p = atomicAdd(&cursor[d1[j] + kN], 1);
    csr[p] = s1[j] + kN;
  }
}
__global__ void count_edges(const int* __restrict__ dst, int* __restrict__ cnt,
                            int ne) {
  const int i = blockIdx.x * blockDim.x + threadIdx.x;
  if (i < ne) atomicAdd(&cnt[dst[i]], 1);
}
__global__ void fill_edges(const int* __restrict__ src, const int* __restrict__ dst,
                           int* __restrict__ cursor, int* __restrict__ csr, int ne) {
  const int i = blockIdx.x * blockDim.x + threadIdx.x;
  if (i < ne) {
    const int p = atomicAdd(&cursor[dst[i]], 1);
    csr[p] = src[i];
  }
}
__global__ void alloc_ranges(const int* __restrict__ cnt, int* __restrict__ start,
                             int* __restrict__ cursor, int* __restrict__ total,
                             int* __restrict__ csr, int n) {
  const int i = blockIdx.x * blockDim.x + threadIdx.x;
  const int lane = threadIdx.x & 63;
  const int v = (i < n) ? cnt[i] : 0;
  int sc = v;
#pragma unroll
  for (int off = 1; off < 64; off <<= 1) {
    const int t = __shfl_up(sc, off);
    if (lane >= off) sc += t;
  }
  const int wtot = __shfl(sc, 63);
  int base = 0;
  if (lane == 63) base = atomicAdd(total, wtot);
  base = __shfl(base, 63);
  const int st = base + sc - v;
  if (i < n) {
    start[i] = st;
    cursor[i] = st + 1;
    csr[st] = i;  // self loop first
  }
}

// ---------------- GAT aggregate, layers 1-2 (f16 h) -------------------
// Per-edge: scalar score gather + leaky + exp + 8 mixed FMAs (dots are
// precomputed). NEXT fuses the NEXT layer's node scores into the output
// stage via linearity (asrc_{l+1} = out_l @ wa_{l+1}): once per node,
// NEXT=1: 64 FMA + 48 shfl (wa[512][8] -> 4 heads);
// NEXT=2: 16 FMA + 12 shfl (wa[512][2] -> 1 head).
template <int NEXT>
__global__ void gat_agg4(const _Float16* __restrict__ h,
                         const float* __restrict__ asrc,
                         const float* __restrict__ adst,
                         const int* __restrict__ start, const int* __restrict__ cnt,
                         const int* __restrict__ csr_src,
                         const float* __restrict__ bias,
                         _Float16* __restrict__ outH,
                         const float* __restrict__ wa,
                         float* __restrict__ aSn, float* __restrict__ aDn,
                         int n_nodes) {
  const int gtid = blockIdx.x * blockDim.x + threadIdx.x;
  const int node = gtid >> 6;
  const int lane = threadIdx.x & 63;
  if (node >= n_nodes) return;
  const int ch = lane * 8;
  const int head = lane >> 4;
  // preload this lane's wa slice (hidden under first gathers)
  float waR[NEXT == 1 ? 64 : 16];
  if constexpr (NEXT == 1) {
#pragma unroll
    for (int q = 0; q < 16; ++q)
      ((float4*)waR)[q] = ((const float4*)(wa + ch * 8))[q];
  } else {
#pragma unroll
    for (int q = 0; q < 4; ++q)
      ((float4*)waR)[q] = ((const float4*)(wa + ch * 2))[q];
  }
  const int s = start[node];
  const int c = cnt[node];
  const float ad = adst[node * 4 + head];
  float d0 = 0.f, d1 = 0.f;
  float a0[8], a1[8];
#pragma unroll
  for (int j = 0; j < 8; ++j) { a0[j] = 0.f; a1[j] = 0.f; }
  int i = 0;
  for (; i + 2 <= c; i += 2) {
    const int s0 = csr_src[s + i];
    const int s1 = csr_src[s + i + 1];
    float e0 = asrc[s0 * 4 + head] + ad;
    float e1 = asrc[s1 * 4 + head] + ad;
    e0 = (e0 > 0.f) ? e0 : kNegSlope * e0;
    e1 = (e1 > 0.f) ? e1 : kNegSlope * e1;
    const float w0 = fexp(e0);
    const float w1 = fexp(e1);
    const half8 v0 = *(const half8*)(h + (size_t)s0 * 512 + ch);
    const half8 v1 = *(const half8*)(h + (size_t)s1 * 512 + ch);
    d0 += w0;
    d1 += w1;
#pragma unroll
    for (int j = 0; j < 8; ++j) {
      a0[j] = fmaf(w0, (float)v0[j], a0[j]);
      a1[j] = fmaf(w1, (float)v1[j], a1[j]);
    }
  }
  if (i < c) {
    const int s0 = csr_src[s + i];
    float e0 = asrc[s0 * 4 + head] + ad;
    e0 = (e0 > 0.f) ? e0 : kNegSlope * e0;
    const float w0 = fexp(e0);
    const half8 v0 = *(const half8*)(h + (size_t)s0 * 512 + ch);
    d0 += w0;
#pragma unroll
    for (int j = 0; j < 8; ++j) a0[j] = fmaf(w0, (float)v0[j], a0[j]);
  }
  const float inv = 1.f / (d0 + d1 + 1e-16f);
  float v[8];
  half8 H;
#pragma unroll
  for (int j = 0; j < 8; ++j) {
    float t = (a0[j] + a1[j]) * inv + bias[ch + j];
    t = (t > 0.f) ? t : (fexp(t) - 1.f);  // elu via hw exp
    v[j] = t;
    H[j] = (_Float16)t;
  }
  *(half8*)(outH + (size_t)node * 512 + ch) = H;
  // ---- next-layer node scores (once per node) ----
  if constexpr (NEXT == 1) {
    float p[8];
#pragma unroll
    for (int j = 0; j < 8; ++j) p[j] = v[0] * waR[j];
#pragma unroll
    for (int jj = 1; jj < 8; ++jj)
#pragma unroll
      for (int j = 0; j < 8; ++j) p[j] = fmaf(v[jj], waR[jj * 8 + j], p[j]);
#pragma unroll
    for (int off = 1; off < 64; off <<= 1)
#pragma unroll
      for (int j = 0; j < 8; ++j) p[j] += __shfl_xor(p[j], off);
    if (lane == 0) {
#pragma unroll
      for (int hd = 0; hd < 4; ++hd) {
        aSn[node * 4 + hd] = p[hd];
        aDn[node * 4 + hd] = p[4 + hd];
      }
    }
  } else {
    float p0 = v[0] * waR[0], p1 = v[0] * waR[1];
#pragma unroll
    for (int jj = 1; jj < 8; ++jj) {
      p0 = fmaf(v[jj], waR[jj * 2], p0);
      p1 = fmaf(v[jj], waR[jj * 2 + 1], p1);
    }
#pragma unroll
    for (int off = 1; off < 64; off <<= 1) {
      p0 += __shfl_xor(p0, off);
      p1 += __shfl_xor(p1, off);
    }
    if (lane == 0) {
      aSn[node] = p0;
      aDn[node] = p1;
    }
  }
}

// ---------- GAT aggregate, layer 3 (H=1, fp32, precomputed dots) ------
__global__ void gat_agg_l3(const float* __restrict__ h,
                           const float* __restrict__ asrc,
                           const float* __restrict__ adst,
                           const int* __restrict__ start, const int* __restrict__ cnt,
                           const int* __restrict__ csr_src,
                           const float* __restrict__ bias,
                           float* __restrict__ out, int n_nodes) {
  const int gtid = blockIdx.x * blockDim.x + threadIdx.x;
  const int node = gtid >> 6;
  const int lane = threadIdx.x & 63;
  if (node >= n_nodes) return;
  const int s = start[node];
  const int c = cnt[node];
  const float ad = adst[node];
  float2 a0 = make_float2(0.f, 0.f);
  float2 a1 = make_float2(0.f, 0.f);
  float d0 = 0.f, d1 = 0.f;
  int i = 0;
  for (; i + 2 <= c; i += 2) {
    const int s0 = csr_src[s + i];
    const int s1 = csr_src[s + i + 1];
    float e0 = asrc[s0] + ad;
    float e1 = asrc[s1] + ad;
    e0 = (e0 > 0.f) ? e0 : kNegSlope * e0;
    e1 = (e1 > 0.f) ? e1 : kNegSlope * e1;
    const float w0 = fexp(e0);
    const float w1 = fexp(e1);
    const float2 v0 = *(const float2*)(h + (size_t)s0 * 128 + lane * 2);
    const float2 v1 = *(const float2*)(h + (size_t)s1 * 128 + lane * 2);
    d0 += w0;
    d1 += w1;
    a0.x = fmaf(w0, v0.x, a0.x); a1.x = fmaf(w1, v1.x, a1.x);
    a0.y = fmaf(w0, v0.y, a0.y); a1.y = fmaf(w1, v1.y, a1.y);
  }
  if (i < c) {
    const int s0 = csr_src[s + i];
    float e0 = asrc[s0] + ad;
    e0 = (e0 > 0.f) ? e0 : kNegSlope * e0;
    const float w0 = fexp(e0);
    const float2 v0 = *(const float2*)(h + (size_t)s0 * 128 + lane * 2);
    d0 += w0;
    a0.x = fmaf(w0, v0.x, a0.x);
    a0.y = fmaf(w0, v0.y, a0.y);
  }
  const float inv = 1.f / (d0 + d1 + 1e-16f);
  *(float2*)(out + (size_t)node * 128 + lane * 2) =
      make_float2((a0.x + a1.x) * inv + bias[lane * 2],
                  (a0.y + a1.y) * inv + bias[lane * 2 + 1]);
}

// ------- global max pool over sorted batch (both encoders, 1 launch) ---
__global__ void pool_max2(const float* __restrict__ x, const int* __restrict__ bt1,
                          const int* __restrict__ bt2, float* __restrict__ emb) {
  __shared__ int lohi[2];
  const int enc = blockIdx.x >> 8;
  const int g = blockIdx.x & 255;
  const int* batch = enc ? bt2 : bt1;
  const float* xx = x + (size_t)enc * kN * 128;
  if (threadIdx.x == 0) {
    int lo = 0, hi = kN;
    while (lo < hi) {
      const int mid = (lo + hi) >> 1;
      if (batch[mid] < g) lo = mid + 1; else hi = mid;
    }
    lohi[0] = lo;
    hi = kN;
    while (lo < hi) {
      const int mid = (lo + hi) >> 1;
      if (batch[mid] < g + 1) lo = mid + 1; else hi = mid;
    }
    lohi[1] = lo;
  }
  __syncthreads();
  const int lo = lohi[0], hi = lohi[1];
  const int c = threadIdx.x;  // 128 channels
  float m = -1e30f;
  for (int nid = lo; nid < hi; ++nid) m = fmaxf(m, xx[(size_t)nid * 128 + c]);
  emb[(size_t)blockIdx.x * 128 + c] = (lo < hi) ? m : 0.f;
}
// ------- single-encoder pool (fallback path) --------------------------
__global__ void pool_max(const float* __restrict__ x, const int* __restrict__ batch,
                         float* __restrict__ emb, int n_nodes) {
  __shared__ int lohi[2];
  const int g = blockIdx.x;
  if (threadIdx.x == 0) {
    int lo = 0, hi = n_nodes;
    while (lo < hi) {
      const int mid = (lo + hi) >> 1;
      if (batch[mid] < g) lo = mid + 1; else hi = mid;
    }
    lohi[0] = lo;
    hi = n_nodes;
    while (lo < hi) {
      const int mid = (lo + hi) >> 1;
      if (batch[mid] < g + 1) lo = mid + 1; else hi = mid;
    }
    lohi[1] = lo;
  }
  __syncthreads();
  const int lo = lohi[0], hi = lohi[1];
  const int c = threadIdx.x;  // 128 channels
  float m = -1e30f;
  for (int nid = lo; nid < hi; ++nid) m = fmaxf(m, x[(size_t)nid * 128 + c]);
  emb[g * 128 + c] = (lo < hi) ? m : 0.f;
}

// ---------------- final MLP head --------------------------------------
__global__ void mlp_head(const float* __restrict__ e1, const float* __restrict__ e2,
                         const float* __restrict__ mw1, const float* __restrict__ mb1,
                         const float* __restrict__ mw2, const float* __restrict__ mb2,
                         float* __restrict__ out) {
  __shared__ float z[256];
  __shared__ float red[128];
  const int g = blockIdx.x;
  const int j = threadIdx.x;  // 128
  z[j] = e1[g * 128 + j];
  z[j + 128] = e2[g * 128 + j];
  __syncthreads();
  float acc = mb1[j];
  for (int k = 0; k < 256; ++k) acc = fmaf(z[k], mw1[k * 128 + j], acc);
  acc = fmaxf(acc, 0.f) * mw2[j];
  red[j] = acc;
  __syncthreads();
  for (int s = 64; s > 0; s >>= 1) {
    if (j < s) red[j] += red[j + s];
    __syncthreads();
  }
  if (j == 0) out[g] = red[0] + mb2[0];
}

// ---------------- launcher --------------------------------------------
namespace {
struct Bufs {
  _Float16 *R1h, *R2h;
  float *R1f, *R2f;
  float *alpha;                       // 18*M floats: aS1 aD1 aS2 aD2 aS3 aD3
  int *cnt, *start, *cursor, *csr, *total;
  _Float16 *Wth1, *Wth2, *Wth3;
  float *wa1, *wa2, *wa3;
  float* emb;
  size_t need;
};

Bufs plan(void* d_ws, int M, int E) {
  Bufs b;
  char* w = (char*)d_ws;
  size_t off = 0;
  auto take = [&](size_t bytes) -> void* {
    void* p = w + off;
    off += (bytes + 255) & ~(size_t)255;
    return p;
  };
  b.R1h = (_Float16*)take((size_t)M * 512 * 2);  // f16 activations
  b.R1f = (float*)b.R1h;                         // layer-3 out alias [M,128]
  b.R2h = (_Float16*)take((size_t)M * 512 * 2);  // h f16; l3 fp32 alias
  b.R2f = (float*)b.R2h;
  b.alpha = (float*)take((size_t)M * 18 * 4);    // per-layer asrc/adst tables
  b.cnt = (int*)take((size_t)M * 4);
  b.start = (int*)take((size_t)M * 4);
  b.cursor = (int*)take((size_t)M * 4);
  b.csr = (int*)take((size_t)E * 4);
  b.total = (int*)take(256);
  b.Wth1 = (_Float16*)take((size_t)64 * 512 * 2);
  b.Wth2 = (_Float16*)take((size_t)512 * 512 * 2);
  b.Wth3 = (_Float16*)take((size_t)512 * 128 * 2);
  b.wa1 = (float*)take((size_t)64 * 8 * 4);
  b.wa2 = (float*)take((size_t)512 * 8 * 4);
  b.wa3 = (float*)take((size_t)512 * 2 * 4);
  b.emb = (float*)take((size_t)2 * kG * 128 * 4);
  b.need = off;
  return b;
}

void run_layers(const Bufs& b, void* const* d_in, int M, hipStream_t stream) {
  const float* b1 = (const float*)d_in[9];
  const float* b2 = (const float*)d_in[13];
  const float* b3 = (const float*)d_in[17];
  float* aS1 = b.alpha;
  float* aD1 = b.alpha + (size_t)M * 4;
  float* aS2 = b.alpha + (size_t)M * 8;
  float* aD2 = b.alpha + (size_t)M * 12;
  float* aS3 = b.alpha + (size_t)M * 16;
  float* aD3 = b.alpha + (size_t)M * 17;
  const int nodeBlocks = (M * 64) / 256;  // 1 wave/node
  const int MT = (M + 255) / 256;         // 256-row tiles
  const int SP = (MT + 7) / 8;            // row-tile groups of 8 (XCD map)

  // layer 1: [M,64] @ [64,512], h -> f16 (A1h aliases R1h)
  gemm_ring<1, 256, 2><<<SP * 16, 512, 0, stream>>>(b.R1h, b.Wth1, b.R2h, M, 512, 64);
  gat_agg4<1><<<nodeBlocks, 256, 0, stream>>>(b.R2h, aS1, aD1, b.start, b.cnt,
                                              b.csr, b1, b.R1h, b.wa2, aS2, aD2, M);
  // layer 2: [M,512] @ [512,512], h -> f16
  gemm_ring<1, 256, 2><<<SP * 16, 512, 0, stream>>>(b.R1h, b.Wth2, b.R2h, M, 512, 512);
  gat_agg4<2><<<nodeBlocks, 256, 0, stream>>>(b.R2h, aS2, aD2, b.start, b.cnt,
                                              b.csr, b2, b.R1h, b.wa3, aS3, aD3, M);
  // layer 3: [M,512] @ [512,128], H=1, no elu, fp32 out
  gemm_ring<0, 128, 1><<<SP * 8, 512, 0, stream>>>(b.R1h, b.Wth3, b.R2f, M, 128, 512);
  gat_agg_l3<<<nodeBlocks, 256, 0, stream>>>(b.R2f, aS3, aD3, b.start, b.cnt,
                                             b.csr, b3, b.R1f, M);
}
}  // namespace

extern "C" void kernel_launch(void* const* d_in, const int* in_sizes, int n_in,
                              void* d_out, int out_size, void* d_ws, size_t ws_size,
                              hipStream_t stream) {
  (void)in_sizes; (void)n_in; (void)out_size;
  const float* W1 = (const float*)d_in[6];
  const float* W2 = (const float*)d_in[10];
  const float* W3 = (const float*)d_in[14];
  const float* mw1 = (const float*)d_in[18];
  const float* mb1 = (const float*)d_in[19];
  const float* mw2 = (const float*)d_in[20];
  const float* mb2 = (const float*)d_in[21];

  // Prefer combined (both encoders batched, M=2N) if it fits the workspace.
  Bufs bc = plan(d_ws, 2 * kN, 2 * kE2);
  const bool combined = bc.need <= ws_size;
  Bufs b = combined ? bc : plan(d_ws, kN, kE2);

  const int wtot = 64 * 512 + 512 * 512 + 512 * 128;
  const int wext = 64 * 8 + 512 * 8 + 512 * 2;
  wt_split_all<<<(wtot + wext + 255) / 256, 256, 0, stream>>>(
      W1, b.Wth1, W2, b.Wth2, W3, b.Wth3,
      (const float*)d_in[7], (const float*)d_in[8],
      (const float*)d_in[11], (const float*)d_in[12],
      (const float*)d_in[15], (const float*)d_in[16],
      b.wa1, b.wa2, b.wa3);
  if (combined) {
    const int M = 2 * kN;
    const int* ei0 = (const int*)d_in[1];
    const int* ei1 = (const int*)d_in[4];
    float* aS1 = b.alpha;
    float* aD1 = b.alpha + (size_t)M * 4;
    prep2<<<(M * 64) / 256, 256, 0, stream>>>(
        (const float*)d_in[0], (const float*)d_in[3], b.R1h, b.cnt, b.total,
        b.wa1, aS1, aD1);
    count_edges2<<<(2 * kE + 255) / 256, 256, 0, stream>>>(ei0 + kE, ei1 + kE,
                                                           b.cnt);
    alloc_ranges<<<(M + 255) / 256, 256, 0, stream>>>(b.cnt, b.start, b.cursor,
                                                      b.total, b.csr, M);
    fill_edges2<<<(2 * kE + 255) / 256, 256, 0, stream>>>(ei0, ei0 + kE, ei1,
                                                          ei1 + kE, b.cursor, b.csr);
    run_layers(b, d_in, M, stream);
    pool_max2<<<2 * kG, 128, 0, stream>>>(b.R1f, (const int*)d_in[2],
                                          (const int*)d_in[5], b.emb);
  } else {
    for (int enc = 0; enc < 2; ++enc) {
      const float* x = (const float*)d_in[enc * 3 + 0];
      const int* ei = (const int*)d_in[enc * 3 + 1];
      const int* batch = (const int*)d_in[enc * 3 + 2];
      float* aS1 = b.alpha;
      float* aD1 = b.alpha + (size_t)kN * 4;
      prep<<<(kN * 64) / 256, 256, 0, stream>>>(x, b.R1h, b.cnt, b.total, b.wa1,
                                                aS1, aD1, kN);
      count_edges<<<(kE + 255) / 256, 256, 0, stream>>>(ei + kE, b.cnt, kE);
      alloc_ranges<<<(kN + 255) / 256, 256, 0, stream>>>(b.cnt, b.start, b.cursor,
                                                         b.total, b.csr, kN);
      fill_edges<<<(kE + 255) / 256, 256, 0, stream>>>(ei, ei + kE, b.cursor, b.csr,
                                                       kE);
      run_layers(b, d_in, kN, stream);
      pool_max<<<kG, 128, 0, stream>>>(b.R1f, batch, b.emb + (size_t)enc * kG * 128,
                                       kN);
    }
  }
  mlp_head<<<kG, 128, 0, stream>>>(b.emb, b.emb + (size_t)kG * 128, mw1, mb1, mw2,
                                   mb2, (float*)d_out);
}

// Round 6
// 668.491 us; speedup vs baseline: 1.2676x; 1.2676x over previous
//
#include <hip/hip_runtime.h>
#include <cstdint>

namespace {
constexpr int kN = 50000;          // nodes per encoder
constexpr int kE = 200000;         // directed edges per encoder (pre self-loop)
constexpr int kE2 = kE + kN;       // with self loops (per encoder)
constexpr int kG = 256;            // graphs per encoder
constexpr float kNegSlope = 0.2f;
}

using half8   = __attribute__((ext_vector_type(8))) _Float16;
using half2v  = __attribute__((ext_vector_type(2))) _Float16;
using floatx4 = __attribute__((ext_vector_type(4))) float;

__device__ __forceinline__ void gld_lds16(const void* g, void* l) {
  __builtin_amdgcn_global_load_lds(
      (const __attribute__((address_space(1))) unsigned int*)g,
      (__attribute__((address_space(3))) unsigned int*)l, 16, 0, 0);
}

// fast exp: e^x = 2^(x*log2(e)) via hardware v_exp_f32 (no libm call)
__device__ __forceinline__ float fexp(float x) {
  return __builtin_amdgcn_exp2f(x * 1.44269504088896f);
}

// ---------------- fp16 MFMA GEMM: C[M,N] = A[M,K] @ B[K,N] -----------
// R15 ring schedule (T3+T4+T5): 4-slot LDS ring, prefetch distance 3,
// counted vmcnt (never 0 in loop), setprio around MFMA clusters. This
// took the l2 GEMM out of the top-5 (was 107us at the 2-phase ceiling).
// R16/R17 lessons: do NOT fuse attention dots here (atomics cost +85us;
// score-by-linearity spills registers) — plain epilogue is best.
template <int OUTF16, int BN, int CT>
__global__ __launch_bounds__(512, 2) void gemm_ring(
    const _Float16* __restrict__ A, const _Float16* __restrict__ B,
    void* __restrict__ Cv, int M, int N, int K) {
  constexpr int ASL = 1024;                // A slots/tile (256 rows x 32k x 2B /16)
  constexpr int BSL = BN * 4;              // B slots/tile (1024 or 512)
  constexpr int SLOT = (ASL + BSL) * 16;   // 32KB or 24KB
  constexpr int LPT = (ASL + BSL) / 512;   // loads/thread/tile: 4 or 3
  constexpr int WN = (BN == 256) ? 4 : 2;  // waves along N
  constexpr int WM = 8 / WN;
  constexpr int WTM = 256 / WM;            // 128 or 64
  constexpr int WTN = BN / WN;             // 64
  constexpr int MI = WTM / 16;             // 8 or 4
  constexpr int NI = WTN / 16;             // 4
  __shared__ alignas(16) char smem[4 * SLOT];  // 128KB or 96KB ring
  const int t = threadIdx.x;
  const int w = t >> 6, l = t & 63;
  const int x = blockIdx.x & 7, s = blockIdx.x >> 3;
  const int col = (CT == 1) ? 0 : (s & (CT - 1));
  const int rt = ((CT == 1) ? s : (s >> 1)) * 8 + x;
  const int bm = rt * 256;
  const int bn = col * BN;
  if (bm >= M) return;  // padded row-tiles: whole block exits (no barrier)
  const int wr = w / WN, wc = w % WN;
  const int quad = l >> 4, lrow = l & 15;

  floatx4 acc[MI][NI];
#pragma unroll
  for (int mi = 0; mi < MI; ++mi)
#pragma unroll
    for (int ni = 0; ni < NI; ++ni) acc[mi][ni] = (floatx4){0.f, 0.f, 0.f, 0.f};

  // stage tile kt's A-part (2 loads) / B-part (LPT-2 loads) into ring slot
  auto stageA = [&](int kt) {
    char* buf = smem + (size_t)(kt & 3) * SLOT;
    int k0 = kt * 32;
    k0 = (k0 > K - 32) ? (K - 32) : k0;  // clamp: beyond-NT garbage stays in-bounds
#pragma unroll
    for (int i = 0; i < 2; ++i) {
      const int sl = i * 512 + t;
      const int row = ((sl >> 6) << 4) + (sl & 15);
      const int q = (sl >> 4) & 3;
      int ga = bm + row;
      ga = (ga < M) ? ga : (M - 1);      // clamp: keep lanes active
      gld_lds16(A + (size_t)ga * K + k0 + q * 8, buf + sl * 16);
    }
  };
  auto stageB = [&](int kt) {
    char* buf = smem + (size_t)(kt & 3) * SLOT + ASL * 16;
    int k0 = kt * 32;
    k0 = (k0 > K - 32) ? (K - 32) : k0;
#pragma unroll
    for (int i = 0; i < LPT - 2; ++i) {
      const int sl = i * 512 + t;
      const int row = ((sl >> 6) << 4) + (sl & 15);
      const int q = (sl >> 4) & 3;
      gld_lds16(B + (size_t)(bn + row) * K + k0 + q * 8, buf + sl * 16);
    }
  };

  // prologue: tiles 0,1,2 in flight (3*LPT loads)
  stageA(0); stageB(0);
  stageA(1); stageB(1);
  stageA(2); stageB(2);

  const int NT = K >> 5;
  for (int kt = 0; kt < NT; ++kt) {
    char* bufc = smem + (size_t)(kt & 3) * SLOT;
    // ---- phase A ----
    stageA(kt + 3);  // 2 loads of tile kt+3 (slot of finished tile kt-1)
    if constexpr (BN == 256)
      asm volatile("s_waitcnt vmcnt(10)" ::: "memory");  // tile kt's 4 landed
    else
      asm volatile("s_waitcnt vmcnt(8)" ::: "memory");   // tile kt's 3 landed
    __builtin_amdgcn_s_barrier();        // all waves: slot[kt&3] ready
    asm volatile("" ::: "memory");
    half8 fa[MI], fb[NI];
#pragma unroll
    for (int ni = 0; ni < NI; ++ni)
      fb[ni] = *(const half8*)(bufc + ASL * 16 + ((wc * NI + ni) << 10) + l * 16);
#pragma unroll
    for (int mi = 0; mi < MI / 2; ++mi)
      fa[mi] = *(const half8*)(bufc + ((wr * MI + mi) << 10) + l * 16);
    __builtin_amdgcn_s_setprio(1);
#pragma unroll
    for (int mi = 0; mi < MI / 2; ++mi)
#pragma unroll
      for (int ni = 0; ni < NI; ++ni)
        acc[mi][ni] = __builtin_amdgcn_mfma_f32_16x16x32_f16(
            fa[mi], fb[ni], acc[mi][ni], 0, 0, 0);
    __builtin_amdgcn_s_setprio(0);
    // ---- phase B ----
    stageB(kt + 3);  // remaining loads of tile kt+3
#pragma unroll
    for (int mi = MI / 2; mi < MI; ++mi)
      fa[mi] = *(const half8*)(bufc + ((wr * MI + mi) << 10) + l * 16);
    __builtin_amdgcn_s_setprio(1);
#pragma unroll
    for (int mi = MI / 2; mi < MI; ++mi)
#pragma unroll
      for (int ni = 0; ni < NI; ++ni)
        acc[mi][ni] = __builtin_amdgcn_mfma_f32_16x16x32_f16(
            fa[mi], fb[ni], acc[mi][ni], 0, 0, 0);
    __builtin_amdgcn_s_setprio(0);
    asm volatile("" ::: "memory");
    __builtin_amdgcn_s_barrier();        // slot[kt&3] reusable for kt+4
  }
  asm volatile("s_waitcnt vmcnt(0)" ::: "memory");  // drain garbage prefetches
  // epilogue: C/D layout col=lane&15, row=quad*4+reg
  const int colbase = bn + wc * WTN + lrow;
#pragma unroll
  for (int mi = 0; mi < MI; ++mi) {
    const int rbase = bm + wr * WTM + mi * 16 + quad * 4;
#pragma unroll
    for (int r = 0; r < 4; ++r) {
      const int grow = rbase + r;
      if (grow < M) {
        if constexpr (OUTF16) {
          _Float16* C = (_Float16*)Cv;
#pragma unroll
          for (int ni = 0; ni < NI; ++ni)
            C[(size_t)grow * N + colbase + ni * 16] = (_Float16)acc[mi][ni][r];
        } else {
          float* C = (float*)Cv;
#pragma unroll
          for (int ni = 0; ni < NI; ++ni)
            C[(size_t)grow * N + colbase + ni * 16] = acc[mi][ni][r];
        }
      }
    }
  }
}

// ------- all three weight transposes + f16 casts (fallback path) ------
__global__ void wt_split_all(const float* __restrict__ W1, _Float16* Th1,
                             const float* __restrict__ W2, _Float16* Th2,
                             const float* __restrict__ W3, _Float16* Th3) {
  int idx = blockIdx.x * blockDim.x + threadIdx.x;
  const float* W;
  _Float16* Th;
  int K, N;
  if (idx < 64 * 512) {
    W = W1; Th = Th1; K = 64; N = 512;
  } else if (idx < 64 * 512 + 512 * 512) {
    idx -= 64 * 512;
    W = W2; Th = Th2; K = 512; N = 512;
  } else if (idx < 64 * 512 + 512 * 512 + 512 * 128) {
    idx -= 64 * 512 + 512 * 512;
    W = W3; Th = Th3; K = 512; N = 128;
  } else {
    return;
  }
  const int k = idx / N;
  const int n = idx - k * N;
  Th[n * K + k] = (_Float16)W[idx];
}

// --- R18 combined prep: x casts + cnt=1 + total=0 + weight transposes -
// (count_edges stays a separate launch: its atomics need cnt initialized,
// and intra-kernel thread ordering is undefined.)
__global__ void prep_all(const float* __restrict__ x0, const float* __restrict__ x1,
                         _Float16* __restrict__ Xh, int* __restrict__ cnt,
                         int* __restrict__ total,
                         const float* __restrict__ W1, _Float16* Th1,
                         const float* __restrict__ W2, _Float16* Th2,
                         const float* __restrict__ W3, _Float16* Th3) {
  const int idx = blockIdx.x * blockDim.x + threadIdx.x;
  const int half = kN * 64;
  if (idx < half) {
    Xh[idx] = (_Float16)x0[idx];
  } else if (idx < 2 * half) {
    Xh[idx] = (_Float16)x1[idx - half];
  } else {
    int e = idx - 2 * half;
    const float* W;
    _Float16* Th;
    int K, N;
    if (e < 64 * 512) {
      W = W1; Th = Th1; K = 64; N = 512;
    } else if (e < 64 * 512 + 512 * 512) {
      e -= 64 * 512;
      W = W2; Th = Th2; K = 512; N = 512;
    } else if (e < 64 * 512 + 512 * 512 + 512 * 128) {
      e -= 64 * 512 + 512 * 512;
      W = W3; Th = Th3; K = 512; N = 128;
    } else {
      W = nullptr; Th = nullptr; K = N = 0;
    }
    if (W) {
      const int k = e / N;
      const int n = e - k * N;
      Th[n * K + k] = (_Float16)W[e];
    }
  }
  if (idx < 2 * kN) cnt[idx] = 1;  // the self loop
  if (idx == 0) *total = 0;
}
// ------- single-encoder prep (fallback path) --------------------------
__global__ void prep(const float* __restrict__ X, _Float16* __restrict__ Xh,
                     int* __restrict__ cnt, int* __restrict__ total, int nsplit,
                     int n) {
  const int idx = blockIdx.x * blockDim.x + threadIdx.x;
  if (idx < nsplit) Xh[idx] = (_Float16)X[idx];
  if (idx < n) cnt[idx] = 1;
  if (idx == 0) *total = 0;
}

// ---------------- CSR (by dst) build ----------------------------------
__global__ void count_edges2(const int* __restrict__ d0, const int* __restrict__ d1,
                             int* __restrict__ cnt) {
  const int i = blockIdx.x * blockDim.x + threadIdx.x;
  if (i < kE) atomicAdd(&cnt[d0[i]], 1);
  else if (i < 2 * kE) atomicAdd(&cnt[d1[i - kE] + kN], 1);
}
__global__ void fill_edges2(const int* __restrict__ s0, const int* __restrict__ d0,
                            const int* __restrict__ s1, const int* __restrict__ d1,
                            int* __restrict__ cursor, int* __restrict__ csr) {
  const int i = blockIdx.x * blockDim.x + threadIdx.x;
  if (i < kE) {
    const int p = atomicAdd(&cursor[d0[i]], 1);
    csr[p] = s0[i];
  } else if (i < 2 * kE) {
    const int j = i - kE;
    const int p = atomicAdd(&cursor[d1[j] + kN], 1);
    csr[p] = s1[j] + kN;
  }
}
__global__ void count_edges(const int* __restrict__ dst, int* __restrict__ cnt,
                            int ne) {
  const int i = blockIdx.x * blockDim.x + threadIdx.x;
  if (i < ne) atomicAdd(&cnt[dst[i]], 1);
}
__global__ void fill_edges(const int* __restrict__ src, const int* __restrict__ dst,
                           int* __restrict__ cursor, int* __restrict__ csr, int ne) {
  const int i = blockIdx.x * blockDim.x + threadIdx.x;
  if (i < ne) {
    const int p = atomicAdd(&cursor[dst[i]], 1);
    csr[p] = src[i];
  }
}
__global__ void alloc_ranges(const int* __restrict__ cnt, int* __restrict__ start,
                             int* __restrict__ cursor, int* __restrict__ total,
                             int* __restrict__ csr, int n) {
  const int i = blockIdx.x * blockDim.x + threadIdx.x;
  const int lane = threadIdx.x & 63;
  const int v = (i < n) ? cnt[i] : 0;
  int sc = v;
#pragma unroll
  for (int off = 1; off < 64; off <<= 1) {
    const int t = __shfl_up(sc, off);
    if (lane >= off) sc += t;
  }
  const int wtot = __shfl(sc, 63);
  int base = 0;
  if (lane == 63) base = atomicAdd(total, wtot);
  base = __shfl(base, 63);
  const int st = base + sc - v;
  if (i < n) {
    start[i] = st;
    cursor[i] = st + 1;
    csr[st] = i;  // self loop first
  }
}

// ---------------- GAT aggregate, layers 1-2 (f16 h) -------------------
// R13 structure (attention dots fused per-edge — proven fastest vs
// separate pass / epilogue-atomics / linearity-spill). R18: 4-edge
// unroll — agg was 42% HBM at 3.4 TB/s random gathers with only 2
// loads in flight; 4 independent 1KB gathers raise memory-level
// parallelism to cover the ~900cy HBM-miss latency.
__global__ void gat_agg4(const _Float16* __restrict__ h,
                         const float* __restrict__ a_src,
                         const float* __restrict__ a_dst,
                         const int* __restrict__ start, const int* __restrict__ cnt,
                         const int* __restrict__ csr_src,
                         const float* __restrict__ bias,
                         _Float16* __restrict__ outH, int n_nodes) {
  const int gtid = blockIdx.x * blockDim.x + threadIdx.x;
  const int node = gtid >> 6;
  const int lane = threadIdx.x & 63;
  if (node >= n_nodes) return;
  const int ch = lane * 8;
  float as_r[8], ad_r[8];
#pragma unroll
  for (int j = 0; j < 8; ++j) {
    as_r[j] = a_src[ch + j];
    ad_r[j] = a_dst[ch + j];
  }
  const int s = start[node];
  const int c = cnt[node];
  // self loop first (csr_src[s] == node): gives both dst-dot and its edge
  const half8 vs = *(const half8*)(h + (size_t)node * 512 + ch);
  float fs[8];
  float t_src = 0.f, t_dst = 0.f;
#pragma unroll
  for (int j = 0; j < 8; ++j) {
    fs[j] = (float)vs[j];
    t_src = fmaf(fs[j], as_r[j], t_src);
    t_dst = fmaf(fs[j], ad_r[j], t_dst);
  }
#pragma unroll
  for (int off = 1; off < 16; off <<= 1) {
    t_src += __shfl_xor(t_src, off);
    t_dst += __shfl_xor(t_dst, off);
  }
  const float ad = t_dst;  // <h[node], a_dst> for this head
  float es = t_src + ad;
  es = (es > 0.f) ? es : kNegSlope * es;
  const float ws = fexp(es);
  float d0 = ws, d1 = 0.f;
  float a0[8], a1[8];
#pragma unroll
  for (int j = 0; j < 8; ++j) {
    a0[j] = ws * fs[j];
    a1[j] = 0.f;
  }
  int i = 1;
  for (; i + 4 <= c; i += 4) {
    const int s0 = csr_src[s + i];
    const int s1 = csr_src[s + i + 1];
    const int s2 = csr_src[s + i + 2];
    const int s3 = csr_src[s + i + 3];
    const half8 v0 = *(const half8*)(h + (size_t)s0 * 512 + ch);
    const half8 v1 = *(const half8*)(h + (size_t)s1 * 512 + ch);
    const half8 v2 = *(const half8*)(h + (size_t)s2 * 512 + ch);
    const half8 v3 = *(const half8*)(h + (size_t)s3 * 512 + ch);
    float f0[8], f1[8], f2[8], f3[8];
    float t0 = 0.f, t1 = 0.f, t2 = 0.f, t3 = 0.f;
#pragma unroll
    for (int j = 0; j < 8; ++j) {
      f0[j] = (float)v0[j]; t0 = fmaf(f0[j], as_r[j], t0);
      f1[j] = (float)v1[j]; t1 = fmaf(f1[j], as_r[j], t1);
      f2[j] = (float)v2[j]; t2 = fmaf(f2[j], as_r[j], t2);
      f3[j] = (float)v3[j]; t3 = fmaf(f3[j], as_r[j], t3);
    }
#pragma unroll
    for (int off = 1; off < 16; off <<= 1) {
      t0 += __shfl_xor(t0, off);
      t1 += __shfl_xor(t1, off);
      t2 += __shfl_xor(t2, off);
      t3 += __shfl_xor(t3, off);
    }
    float e0 = t0 + ad, e1 = t1 + ad, e2 = t2 + ad, e3 = t3 + ad;
    e0 = (e0 > 0.f) ? e0 : kNegSlope * e0;
    e1 = (e1 > 0.f) ? e1 : kNegSlope * e1;
    e2 = (e2 > 0.f) ? e2 : kNegSlope * e2;
    e3 = (e3 > 0.f) ? e3 : kNegSlope * e3;
    const float w0 = fexp(e0), w1 = fexp(e1), w2 = fexp(e2), w3 = fexp(e3);
    d0 += w0 + w2;
    d1 += w1 + w3;
#pragma unroll
    for (int j = 0; j < 8; ++j) {
      a0[j] = fmaf(w0, f0[j], a0[j]);
      a1[j] = fmaf(w1, f1[j], a1[j]);
      a0[j] = fmaf(w2, f2[j], a0[j]);
      a1[j] = fmaf(w3, f3[j], a1[j]);
    }
  }
  for (; i + 2 <= c; i += 2) {
    const int s0 = csr_src[s + i];
    const int s1 = csr_src[s + i + 1];
    const half8 v0 = *(const half8*)(h + (size_t)s0 * 512 + ch);
    const half8 v1 = *(const half8*)(h + (size_t)s1 * 512 + ch);
    float f0[8], f1[8];
    float t0 = 0.f, t1 = 0.f;
#pragma unroll
    for (int j = 0; j < 8; ++j) {
      f0[j] = (float)v0[j]; t0 = fmaf(f0[j], as_r[j], t0);
      f1[j] = (float)v1[j]; t1 = fmaf(f1[j], as_r[j], t1);
    }
#pragma unroll
    for (int off = 1; off < 16; off <<= 1) {
      t0 += __shfl_xor(t0, off);
      t1 += __shfl_xor(t1, off);
    }
    float e0 = t0 + ad, e1 = t1 + ad;
    e0 = (e0 > 0.f) ? e0 : kNegSlope * e0;
    e1 = (e1 > 0.f) ? e1 : kNegSlope * e1;
    const float w0 = fexp(e0), w1 = fexp(e1);
    d0 += w0;
    d1 += w1;
#pragma unroll
    for (int j = 0; j < 8; ++j) {
      a0[j] = fmaf(w0, f0[j], a0[j]);
      a1[j] = fmaf(w1, f1[j], a1[j]);
    }
  }
  if (i < c) {
    const int s0 = csr_src[s + i];
    const half8 v0 = *(const half8*)(h + (size_t)s0 * 512 + ch);
    float f0[8];
    float t0 = 0.f;
#pragma unroll
    for (int j = 0; j < 8; ++j) {
      f0[j] = (float)v0[j];
      t0 = fmaf(f0[j], as_r[j], t0);
    }
#pragma unroll
    for (int off = 1; off < 16; off <<= 1) t0 += __shfl_xor(t0, off);
    float e0 = t0 + ad;
    e0 = (e0 > 0.f) ? e0 : kNegSlope * e0;
    const float w0 = fexp(e0);
    d0 += w0;
#pragma unroll
    for (int j = 0; j < 8; ++j) a0[j] = fmaf(w0, f0[j], a0[j]);
  }
  const float inv = 1.f / (d0 + d1 + 1e-16f);
  half8 H;
#pragma unroll
  for (int j = 0; j < 8; ++j) {
    float v = (a0[j] + a1[j]) * inv + bias[ch + j];
    v = (v > 0.f) ? v : (fexp(v) - 1.f);  // elu via hw exp
    H[j] = (_Float16)v;
  }
  *(half8*)(outH + (size_t)node * 512 + ch) = H;
}

// ---------- GAT aggregate, layer 3 (H=1, f16 h, fused dots) -----------
// R18: h3 now f16 (halves the 512B/edge gather to 256B) + 4-edge unroll.
__global__ void gat_agg_l3(const _Float16* __restrict__ h,
                           const float* __restrict__ a_src,
                           const float* __restrict__ a_dst,
                           const int* __restrict__ start, const int* __restrict__ cnt,
                           const int* __restrict__ csr_src,
                           const float* __restrict__ bias,
                           float* __restrict__ out, int n_nodes) {
  const int gtid = blockIdx.x * blockDim.x + threadIdx.x;
  const int node = gtid >> 6;
  const int lane = threadIdx.x & 63;
  if (node >= n_nodes) return;
  const float2 asv = *(const float2*)(a_src + lane * 2);
  const float2 adv = *(const float2*)(a_dst + lane * 2);
  const int s = start[node];
  const int c = cnt[node];
  // self loop first: dst-dot + its own edge
  const half2v vs = *(const half2v*)(h + (size_t)node * 128 + lane * 2);
  const float vsx = (float)vs[0], vsy = (float)vs[1];
  float t_src = fmaf(vsx, asv.x, vsy * asv.y);
  float t_dst = fmaf(vsx, adv.x, vsy * adv.y);
#pragma unroll
  for (int off = 1; off < 64; off <<= 1) {
    t_src += __shfl_xor(t_src, off);
    t_dst += __shfl_xor(t_dst, off);
  }
  const float ad = t_dst;
  float es = t_src + ad;
  es = (es > 0.f) ? es : kNegSlope * es;
  const float ws = fexp(es);
  float2 a0 = make_float2(ws * vsx, ws * vsy);
  float2 a1 = make_float2(0.f, 0.f);
  float d0 = ws, d1 = 0.f;
  int i = 1;
  for (; i + 4 <= c; i += 4) {
    const int s0 = csr_src[s + i];
    const int s1 = csr_src[s + i + 1];
    const int s2 = csr_src[s + i + 2];
    const int s3 = csr_src[s + i + 3];
    const half2v v0 = *(const half2v*)(h + (size_t)s0 * 128 + lane * 2);
    const half2v v1 = *(const half2v*)(h + (size_t)s1 * 128 + lane * 2);
    const half2v v2 = *(const half2v*)(h + (size_t)s2 * 128 + lane * 2);
    const half2v v3 = *(const half2v*)(h + (size_t)s3 * 128 + lane * 2);
    const float x0 = (float)v0[0], y0 = (float)v0[1];
    const float x1 = (float)v1[0], y1 = (float)v1[1];
    const float x2 = (float)v2[0], y2 = (float)v2[1];
    const float x3 = (float)v3[0], y3 = (float)v3[1];
    float t0 = fmaf(x0, asv.x, y0 * asv.y);
    float t1 = fmaf(x1, asv.x, y1 * asv.y);
    float t2 = fmaf(x2, asv.x, y2 * asv.y);
    float t3 = fmaf(x3, asv.x, y3 * asv.y);
#pragma unroll
    for (int off = 1; off < 64; off <<= 1) {
      t0 += __shfl_xor(t0, off);
      t1 += __shfl_xor(t1, off);
      t2 += __shfl_xor(t2, off);
      t3 += __shfl_xor(t3, off);
    }
    float e0 = t0 + ad, e1 = t1 + ad, e2 = t2 + ad, e3 = t3 + ad;
    e0 = (e0 > 0.f) ? e0 : kNegSlope * e0;
    e1 = (e1 > 0.f) ? e1 : kNegSlope * e1;
    e2 = (e2 > 0.f) ? e2 : kNegSlope * e2;
    e3 = (e3 > 0.f) ? e3 : kNegSlope * e3;
    const float w0 = fexp(e0), w1 = fexp(e1), w2 = fexp(e2), w3 = fexp(e3);
    d0 += w0 + w2;
    d1 += w1 + w3;
    a0.x = fmaf(w0, x0, a0.x); a0.x = fmaf(w2, x2, a0.x);
    a0.y = fmaf(w0, y0, a0.y); a0.y = fmaf(w2, y2, a0.y);
    a1.x = fmaf(w1, x1, a1.x); a1.x = fmaf(w3, x3, a1.x);
    a1.y = fmaf(w1, y1, a1.y); a1.y = fmaf(w3, y3, a1.y);
  }
  for (; i + 2 <= c; i += 2) {
    const int s0 = csr_src[s + i];
    const int s1 = csr_src[s + i + 1];
    const half2v v0 = *(const half2v*)(h + (size_t)s0 * 128 + lane * 2);
    const half2v v1 = *(const half2v*)(h + (size_t)s1 * 128 + lane * 2);
    const float x0 = (float)v0[0], y0 = (float)v0[1];
    const float x1 = (float)v1[0], y1 = (float)v1[1];
    float t0 = fmaf(x0, asv.x, y0 * asv.y);
    float t1 = fmaf(x1, asv.x, y1 * asv.y);
#pragma unroll
    for (int off = 1; off < 64; off <<= 1) {
      t0 += __shfl_xor(t0, off);
      t1 += __shfl_xor(t1, off);
    }
    float e0 = t0 + ad, e1 = t1 + ad;
    e0 = (e0 > 0.f) ? e0 : kNegSlope * e0;
    e1 = (e1 > 0.f) ? e1 : kNegSlope * e1;
    const float w0 = fexp(e0), w1 = fexp(e1);
    d0 += w0;
    d1 += w1;
    a0.x = fmaf(w0, x0, a0.x); a1.x = fmaf(w1, x1, a1.x);
    a0.y = fmaf(w0, y0, a0.y); a1.y = fmaf(w1, y1, a1.y);
  }
  if (i < c) {
    const int s0 = csr_src[s + i];
    const half2v v0 = *(const half2v*)(h + (size_t)s0 * 128 + lane * 2);
    const float x0 = (float)v0[0], y0 = (float)v0[1];
    float t0 = fmaf(x0, asv.x, y0 * asv.y);
#pragma unroll
    for (int off = 1; off < 64; off <<= 1) t0 += __shfl_xor(t0, off);
    float e0 = t0 + ad;
    e0 = (e0 > 0.f) ? e0 : kNegSlope * e0;
    const float w0 = fexp(e0);
    d0 += w0;
    a0.x = fmaf(w0, x0, a0.x);
    a0.y = fmaf(w0, y0, a0.y);
  }
  const float inv = 1.f / (d0 + d1 + 1e-16f);
  *(float2*)(out + (size_t)node * 128 + lane * 2) =
      make_float2((a0.x + a1.x) * inv + bias[lane * 2],
                  (a0.y + a1.y) * inv + bias[lane * 2 + 1]);
}

// ------- global max pool over sorted batch (both encoders, 1 launch) ---
__global__ void pool_max2(const float* __restrict__ x, const int* __restrict__ bt1,
                          const int* __restrict__ bt2, float* __restrict__ emb) {
  __shared__ int lohi[2];
  const int enc = blockIdx.x >> 8;
  const int g = blockIdx.x & 255;
  const int* batch = enc ? bt2 : bt1;
  const float* xx = x + (size_t)enc * kN * 128;
  if (threadIdx.x == 0) {
    int lo = 0, hi = kN;
    while (lo < hi) {
      const int mid = (lo + hi) >> 1;
      if (batch[mid] < g) lo = mid + 1; else hi = mid;
    }
    lohi[0] = lo;
    hi = kN;
    while (lo < hi) {
      const int mid = (lo + hi) >> 1;
      if (batch[mid] < g + 1) lo = mid + 1; else hi = mid;
    }
    lohi[1] = lo;
  }
  __syncthreads();
  const int lo = lohi[0], hi = lohi[1];
  const int c = threadIdx.x;  // 128 channels
  float m = -1e30f;
  for (int nid = lo; nid < hi; ++nid) m = fmaxf(m, xx[(size_t)nid * 128 + c]);
  emb[(size_t)blockIdx.x * 128 + c] = (lo < hi) ? m : 0.f;
}
// ------- single-encoder pool (fallback path) --------------------------
__global__ void pool_max(const float* __restrict__ x, const int* __restrict__ batch,
                         float* __restrict__ emb, int n_nodes) {
  __shared__ int lohi[2];
  const int g = blockIdx.x;
  if (threadIdx.x == 0) {
    int lo = 0, hi = n_nodes;
    while (lo < hi) {
      const int mid = (lo + hi) >> 1;
      if (batch[mid] < g) lo = mid + 1; else hi = mid;
    }
    lohi[0] = lo;
    hi = n_nodes;
    while (lo < hi) {
      const int mid = (lo + hi) >> 1;
      if (batch[mid] < g + 1) lo = mid + 1; else hi = mid;
    }
    lohi[1] = lo;
  }
  __syncthreads();
  const int lo = lohi[0], hi = lohi[1];
  const int c = threadIdx.x;  // 128 channels
  float m = -1e30f;
  for (int nid = lo; nid < hi; ++nid) m = fmaxf(m, x[(size_t)nid * 128 + c]);
  emb[g * 128 + c] = (lo < hi) ? m : 0.f;
}

// ---------------- final MLP head --------------------------------------
__global__ void mlp_head(const float* __restrict__ e1, const float* __restrict__ e2,
                         const float* __restrict__ mw1, const float* __restrict__ mb1,
                         const float* __restrict__ mw2, const float* __restrict__ mb2,
                         float* __restrict__ out) {
  __shared__ float z[256];
  __shared__ float red[128];
  const int g = blockIdx.x;
  const int j = threadIdx.x;  // 128
  z[j] = e1[g * 128 + j];
  z[j + 128] = e2[g * 128 + j];
  __syncthreads();
  float acc = mb1[j];
  for (int k = 0; k < 256; ++k) acc = fmaf(z[k], mw1[k * 128 + j], acc);
  acc = fmaxf(acc, 0.f) * mw2[j];
  red[j] = acc;
  __syncthreads();
  for (int s = 64; s > 0; s >>= 1) {
    if (j < s) red[j] += red[j + s];
    __syncthreads();
  }
  if (j == 0) out[g] = red[0] + mb2[0];
}

// ---------------- launcher --------------------------------------------
namespace {
struct Bufs {
  _Float16 *R1h, *R2h;
  float *R1f, *R2f, *asrc, *adst;
  int *cnt, *start, *cursor, *csr, *total;
  _Float16 *Wth1, *Wth2, *Wth3;
  float* emb;
  size_t need;
};

Bufs plan(void* d_ws, int M, int E) {
  Bufs b;
  char* w = (char*)d_ws;
  size_t off = 0;
  auto take = [&](size_t bytes) -> void* {
    void* p = w + off;
    off += (bytes + 255) & ~(size_t)255;
    return p;
  };
  b.R1h = (_Float16*)take((size_t)M * 512 * 2);  // f16 activations
  b.R1f = (float*)b.R1h;                         // layer-3 out alias [M,128]
  b.R2h = (_Float16*)take((size_t)M * 512 * 2);  // h f16 (l3 h f16 [M,128])
  b.R2f = (float*)b.R2h;
  b.asrc = (float*)take((size_t)M * 4 * 4);      // (kept for ws layout stability)
  b.adst = (float*)take((size_t)M * 4 * 4);
  b.cnt = (int*)take((size_t)M * 4);
  b.start = (int*)take((size_t)M * 4);
  b.cursor = (int*)take((size_t)M * 4);
  b.csr = (int*)take((size_t)E * 4);
  b.total = (int*)take(256);
  b.Wth1 = (_Float16*)take((size_t)64 * 512 * 2);
  b.Wth2 = (_Float16*)take((size_t)512 * 512 * 2);
  b.Wth3 = (_Float16*)take((size_t)512 * 128 * 2);
  b.emb = (float*)take((size_t)2 * kG * 128 * 4);
  b.need = off;
  return b;
}

void run_layers(const Bufs& b, void* const* d_in, int M, hipStream_t stream) {
  const float* as1 = (const float*)d_in[7];
  const float* ad1 = (const float*)d_in[8];
  const float* b1 = (const float*)d_in[9];
  const float* as2 = (const float*)d_in[11];
  const float* ad2 = (const float*)d_in[12];
  const float* b2 = (const float*)d_in[13];
  const float* as3 = (const float*)d_in[15];
  const float* ad3 = (const float*)d_in[16];
  const float* b3 = (const float*)d_in[17];
  const int nodeBlocks = (M * 64) / 256;  // 1 wave/node
  const int MT = (M + 255) / 256;         // 256-row tiles
  const int SP = (MT + 7) / 8;            // row-tile groups of 8 (XCD map)

  // layer 1: [M,64] @ [64,512], h -> f16 (A1h aliases R1h)
  gemm_ring<1, 256, 2><<<SP * 16, 512, 0, stream>>>(b.R1h, b.Wth1, b.R2h, M, 512, 64);
  gat_agg4<<<nodeBlocks, 256, 0, stream>>>(b.R2h, as1, ad1, b.start, b.cnt,
                                           b.csr, b1, b.R1h, M);
  // layer 2: [M,512] @ [512,512], h -> f16
  gemm_ring<1, 256, 2><<<SP * 16, 512, 0, stream>>>(b.R1h, b.Wth2, b.R2h, M, 512, 512);
  gat_agg4<<<nodeBlocks, 256, 0, stream>>>(b.R2h, as2, ad2, b.start, b.cnt,
                                           b.csr, b2, b.R1h, M);
  // layer 3: [M,512] @ [512,128], H=1, no elu, h -> f16 (R18)
  gemm_ring<1, 128, 1><<<SP * 8, 512, 0, stream>>>(b.R1h, b.Wth3, b.R2h, M, 128, 512);
  gat_agg_l3<<<nodeBlocks, 256, 0, stream>>>(b.R2h, as3, ad3, b.start, b.cnt,
                                             b.csr, b3, b.R1f, M);
}
}  // namespace

extern "C" void kernel_launch(void* const* d_in, const int* in_sizes, int n_in,
                              void* d_out, int out_size, void* d_ws, size_t ws_size,
                              hipStream_t stream) {
  (void)in_sizes; (void)n_in; (void)out_size;
  const float* W1 = (const float*)d_in[6];
  const float* W2 = (const float*)d_in[10];
  const float* W3 = (const float*)d_in[14];
  const float* mw1 = (const float*)d_in[18];
  const float* mb1 = (const float*)d_in[19];
  const float* mw2 = (const float*)d_in[20];
  const float* mb2 = (const float*)d_in[21];

  // Prefer combined (both encoders batched, M=2N) if it fits the workspace.
  Bufs bc = plan(d_ws, 2 * kN, 2 * kE2);
  const bool combined = bc.need <= ws_size;
  Bufs b = combined ? bc : plan(d_ws, kN, kE2);

  const int wtot = 64 * 512 + 512 * 512 + 512 * 128;
  if (combined) {
    const int M = 2 * kN;
    const int* ei0 = (const int*)d_in[1];
    const int* ei1 = (const int*)d_in[4];
    prep_all<<<(M * 64 + wtot + 255) / 256, 256, 0, stream>>>(
        (const float*)d_in[0], (const float*)d_in[3], b.R1h, b.cnt, b.total,
        W1, b.Wth1, W2, b.Wth2, W3, b.Wth3);
    count_edges2<<<(2 * kE + 255) / 256, 256, 0, stream>>>(ei0 + kE, ei1 + kE,
                                                           b.cnt);
    alloc_ranges<<<(M + 255) / 256, 256, 0, stream>>>(b.cnt, b.start, b.cursor,
                                                      b.total, b.csr, M);
    fill_edges2<<<(2 * kE + 255) / 256, 256, 0, stream>>>(ei0, ei0 + kE, ei1,
                                                          ei1 + kE, b.cursor, b.csr);
    run_layers(b, d_in, M, stream);
    pool_max2<<<2 * kG, 128, 0, stream>>>(b.R1f, (const int*)d_in[2],
                                          (const int*)d_in[5], b.emb);
  } else {
    wt_split_all<<<(wtot + 255) / 256, 256, 0, stream>>>(W1, b.Wth1, W2, b.Wth2,
                                                         W3, b.Wth3);
    for (int enc = 0; enc < 2; ++enc) {
      const float* x = (const float*)d_in[enc * 3 + 0];
      const int* ei = (const int*)d_in[enc * 3 + 1];
      const int* batch = (const int*)d_in[enc * 3 + 2];
      prep<<<(kN * 64 + 255) / 256, 256, 0, stream>>>(x, b.R1h, b.cnt, b.total,
                                                      kN * 64, kN);
      count_edges<<<(kE + 255) / 256, 256, 0, stream>>>(ei + kE, b.cnt, kE);
      alloc_ranges<<<(kN + 255) / 256, 256, 0, stream>>>(b.cnt, b.start, b.cursor,
                                                         b.total, b.csr, kN);
      fill_edges<<<(kE + 255) / 256, 256, 0, stream>>>(ei, ei + kE, b.cursor, b.csr,
                                                       kE);
      run_layers(b, d_in, kN, stream);
      pool_max<<<kG, 128, 0, stream>>>(b.R1f, batch, b.emb + (size_t)enc * kG * 128,
                                       kN);
    }
  }
  mlp_head<<<kG, 128, 0, stream>>>(b.emb, b.emb + (size_t)kG * 128, mw1, mb1, mw2,
                                   mb2, (float*)d_out);
}

// Round 7
// 642.520 us; speedup vs baseline: 1.3188x; 1.0404x over previous
//
#include <hip/hip_runtime.h>
#include <cstdint>

namespace {
constexpr int kN = 50000;          // nodes per encoder
constexpr int kE = 200000;         // directed edges per encoder (pre self-loop)
constexpr int kE2 = kE + kN;       // with self loops (per encoder)
constexpr int kG = 256;            // graphs per encoder
constexpr float kNegSlope = 0.2f;
}

using half8   = __attribute__((ext_vector_type(8))) _Float16;
using half2v  = __attribute__((ext_vector_type(2))) _Float16;
using floatx4 = __attribute__((ext_vector_type(4))) float;

__device__ __forceinline__ void gld_lds16(const void* g, void* l) {
  __builtin_amdgcn_global_load_lds(
      (const __attribute__((address_space(1))) unsigned int*)g,
      (__attribute__((address_space(3))) unsigned int*)l, 16, 0, 0);
}

// fast exp: e^x = 2^(x*log2(e)) via hardware v_exp_f32 (no libm call)
__device__ __forceinline__ float fexp(float x) {
  return __builtin_amdgcn_exp2f(x * 1.44269504088896f);
}

// ---------------- fp16 MFMA GEMM: C[M,N] = A[M,K] @ B[K,N] -----------
// R15 ring schedule (T3+T4+T5): 4-slot LDS ring, prefetch distance 3,
// counted vmcnt (never 0 in loop), setprio around MFMA clusters.
// R16/R17 lessons: no dot-fusion here (atomics / register spill).
template <int OUTF16, int BN, int CT>
__global__ __launch_bounds__(512, 2) void gemm_ring(
    const _Float16* __restrict__ A, const _Float16* __restrict__ B,
    void* __restrict__ Cv, int M, int N, int K) {
  constexpr int ASL = 1024;                // A slots/tile (256 rows x 32k x 2B /16)
  constexpr int BSL = BN * 4;              // B slots/tile (1024 or 512)
  constexpr int SLOT = (ASL + BSL) * 16;   // 32KB or 24KB
  constexpr int LPT = (ASL + BSL) / 512;   // loads/thread/tile: 4 or 3
  constexpr int WN = (BN == 256) ? 4 : 2;  // waves along N
  constexpr int WM = 8 / WN;
  constexpr int WTM = 256 / WM;            // 128 or 64
  constexpr int WTN = BN / WN;             // 64
  constexpr int MI = WTM / 16;             // 8 or 4
  constexpr int NI = WTN / 16;             // 4
  __shared__ alignas(16) char smem[4 * SLOT];  // 128KB or 96KB ring
  const int t = threadIdx.x;
  const int w = t >> 6, l = t & 63;
  const int x = blockIdx.x & 7, s = blockIdx.x >> 3;
  const int col = (CT == 1) ? 0 : (s & (CT - 1));
  const int rt = ((CT == 1) ? s : (s >> 1)) * 8 + x;
  const int bm = rt * 256;
  const int bn = col * BN;
  if (bm >= M) return;  // padded row-tiles: whole block exits (no barrier)
  const int wr = w / WN, wc = w % WN;
  const int quad = l >> 4, lrow = l & 15;

  floatx4 acc[MI][NI];
#pragma unroll
  for (int mi = 0; mi < MI; ++mi)
#pragma unroll
    for (int ni = 0; ni < NI; ++ni) acc[mi][ni] = (floatx4){0.f, 0.f, 0.f, 0.f};

  // stage tile kt's A-part (2 loads) / B-part (LPT-2 loads) into ring slot
  auto stageA = [&](int kt) {
    char* buf = smem + (size_t)(kt & 3) * SLOT;
    int k0 = kt * 32;
    k0 = (k0 > K - 32) ? (K - 32) : k0;  // clamp: beyond-NT garbage stays in-bounds
#pragma unroll
    for (int i = 0; i < 2; ++i) {
      const int sl = i * 512 + t;
      const int row = ((sl >> 6) << 4) + (sl & 15);
      const int q = (sl >> 4) & 3;
      int ga = bm + row;
      ga = (ga < M) ? ga : (M - 1);      // clamp: keep lanes active
      gld_lds16(A + (size_t)ga * K + k0 + q * 8, buf + sl * 16);
    }
  };
  auto stageB = [&](int kt) {
    char* buf = smem + (size_t)(kt & 3) * SLOT + ASL * 16;
    int k0 = kt * 32;
    k0 = (k0 > K - 32) ? (K - 32) : k0;
#pragma unroll
    for (int i = 0; i < LPT - 2; ++i) {
      const int sl = i * 512 + t;
      const int row = ((sl >> 6) << 4) + (sl & 15);
      const int q = (sl >> 4) & 3;
      gld_lds16(B + (size_t)(bn + row) * K + k0 + q * 8, buf + sl * 16);
    }
  };

  // prologue: tiles 0,1,2 in flight (3*LPT loads)
  stageA(0); stageB(0);
  stageA(1); stageB(1);
  stageA(2); stageB(2);

  const int NT = K >> 5;
  for (int kt = 0; kt < NT; ++kt) {
    char* bufc = smem + (size_t)(kt & 3) * SLOT;
    // ---- phase A ----
    stageA(kt + 3);  // 2 loads of tile kt+3 (slot of finished tile kt-1)
    if constexpr (BN == 256)
      asm volatile("s_waitcnt vmcnt(10)" ::: "memory");  // tile kt's 4 landed
    else
      asm volatile("s_waitcnt vmcnt(8)" ::: "memory");   // tile kt's 3 landed
    __builtin_amdgcn_s_barrier();        // all waves: slot[kt&3] ready
    asm volatile("" ::: "memory");
    half8 fa[MI], fb[NI];
#pragma unroll
    for (int ni = 0; ni < NI; ++ni)
      fb[ni] = *(const half8*)(bufc + ASL * 16 + ((wc * NI + ni) << 10) + l * 16);
#pragma unroll
    for (int mi = 0; mi < MI / 2; ++mi)
      fa[mi] = *(const half8*)(bufc + ((wr * MI + mi) << 10) + l * 16);
    __builtin_amdgcn_s_setprio(1);
#pragma unroll
    for (int mi = 0; mi < MI / 2; ++mi)
#pragma unroll
      for (int ni = 0; ni < NI; ++ni)
        acc[mi][ni] = __builtin_amdgcn_mfma_f32_16x16x32_f16(
            fa[mi], fb[ni], acc[mi][ni], 0, 0, 0);
    __builtin_amdgcn_s_setprio(0);
    // ---- phase B ----
    stageB(kt + 3);  // remaining loads of tile kt+3
#pragma unroll
    for (int mi = MI / 2; mi < MI; ++mi)
      fa[mi] = *(const half8*)(bufc + ((wr * MI + mi) << 10) + l * 16);
    __builtin_amdgcn_s_setprio(1);
#pragma unroll
    for (int mi = MI / 2; mi < MI; ++mi)
#pragma unroll
      for (int ni = 0; ni < NI; ++ni)
        acc[mi][ni] = __builtin_amdgcn_mfma_f32_16x16x32_f16(
            fa[mi], fb[ni], acc[mi][ni], 0, 0, 0);
    __builtin_amdgcn_s_setprio(0);
    asm volatile("" ::: "memory");
    __builtin_amdgcn_s_barrier();        // slot[kt&3] reusable for kt+4
  }
  asm volatile("s_waitcnt vmcnt(0)" ::: "memory");  // drain garbage prefetches
  // epilogue: C/D layout col=lane&15, row=quad*4+reg
  const int colbase = bn + wc * WTN + lrow;
#pragma unroll
  for (int mi = 0; mi < MI; ++mi) {
    const int rbase = bm + wr * WTM + mi * 16 + quad * 4;
#pragma unroll
    for (int r = 0; r < 4; ++r) {
      const int grow = rbase + r;
      if (grow < M) {
        if constexpr (OUTF16) {
          _Float16* C = (_Float16*)Cv;
#pragma unroll
          for (int ni = 0; ni < NI; ++ni)
            C[(size_t)grow * N + colbase + ni * 16] = (_Float16)acc[mi][ni][r];
        } else {
          float* C = (float*)Cv;
#pragma unroll
          for (int ni = 0; ni < NI; ++ni)
            C[(size_t)grow * N + colbase + ni * 16] = acc[mi][ni][r];
        }
      }
    }
  }
}

// ------- all three weight transposes + f16 casts (fallback path) ------
__global__ void wt_split_all(const float* __restrict__ W1, _Float16* Th1,
                             const float* __restrict__ W2, _Float16* Th2,
                             const float* __restrict__ W3, _Float16* Th3) {
  int idx = blockIdx.x * blockDim.x + threadIdx.x;
  const float* W;
  _Float16* Th;
  int K, N;
  if (idx < 64 * 512) {
    W = W1; Th = Th1; K = 64; N = 512;
  } else if (idx < 64 * 512 + 512 * 512) {
    idx -= 64 * 512;
    W = W2; Th = Th2; K = 512; N = 512;
  } else if (idx < 64 * 512 + 512 * 512 + 512 * 128) {
    idx -= 64 * 512 + 512 * 512;
    W = W3; Th = Th3; K = 512; N = 128;
  } else {
    return;
  }
  const int k = idx / N;
  const int n = idx - k * N;
  Th[n * K + k] = (_Float16)W[idx];
}

// --- combined prep: x casts + cnt=1 + total=0 + weight transposes -----
__global__ void prep_all(const float* __restrict__ x0, const float* __restrict__ x1,
                         _Float16* __restrict__ Xh, int* __restrict__ cnt,
                         int* __restrict__ total,
                         const float* __restrict__ W1, _Float16* Th1,
                         const float* __restrict__ W2, _Float16* Th2,
                         const float* __restrict__ W3, _Float16* Th3) {
  const int idx = blockIdx.x * blockDim.x + threadIdx.x;
  const int half = kN * 64;
  if (idx < half) {
    Xh[idx] = (_Float16)x0[idx];
  } else if (idx < 2 * half) {
    Xh[idx] = (_Float16)x1[idx - half];
  } else {
    int e = idx - 2 * half;
    const float* W;
    _Float16* Th;
    int K, N;
    if (e < 64 * 512) {
      W = W1; Th = Th1; K = 64; N = 512;
    } else if (e < 64 * 512 + 512 * 512) {
      e -= 64 * 512;
      W = W2; Th = Th2; K = 512; N = 512;
    } else if (e < 64 * 512 + 512 * 512 + 512 * 128) {
      e -= 64 * 512 + 512 * 512;
      W = W3; Th = Th3; K = 512; N = 128;
    } else {
      W = nullptr; Th = nullptr; K = N = 0;
    }
    if (W) {
      const int k = e / N;
      const int n = e - k * N;
      Th[n * K + k] = (_Float16)W[e];
    }
  }
  if (idx < 2 * kN) cnt[idx] = 1;  // the self loop
  if (idx == 0) *total = 0;
}
// ------- single-encoder prep (fallback path) --------------------------
__global__ void prep(const float* __restrict__ X, _Float16* __restrict__ Xh,
                     int* __restrict__ cnt, int* __restrict__ total, int nsplit,
                     int n) {
  const int idx = blockIdx.x * blockDim.x + threadIdx.x;
  if (idx < nsplit) Xh[idx] = (_Float16)X[idx];
  if (idx < n) cnt[idx] = 1;
  if (idx == 0) *total = 0;
}

// ---------------- CSR (by dst) build ----------------------------------
__global__ void count_edges2(const int* __restrict__ d0, const int* __restrict__ d1,
                             int* __restrict__ cnt) {
  const int i = blockIdx.x * blockDim.x + threadIdx.x;
  if (i < kE) atomicAdd(&cnt[d0[i]], 1);
  else if (i < 2 * kE) atomicAdd(&cnt[d1[i - kE] + kN], 1);
}
__global__ void fill_edges2(const int* __restrict__ s0, const int* __restrict__ d0,
                            const int* __restrict__ s1, const int* __restrict__ d1,
                            int* __restrict__ cursor, int* __restrict__ csr) {
  const int i = blockIdx.x * blockDim.x + threadIdx.x;
  if (i < kE) {
    const int p = atomicAdd(&cursor[d0[i]], 1);
    csr[p] = s0[i];
  } else if (i < 2 * kE) {
    const int j = i - kE;
    const int p = atomicAdd(&cursor[d1[j] + kN], 1);
    csr[p] = s1[j] + kN;
  }
}
__global__ void count_edges(const int* __restrict__ dst, int* __restrict__ cnt,
                            int ne) {
  const int i = blockIdx.x * blockDim.x + threadIdx.x;
  if (i < ne) atomicAdd(&cnt[dst[i]], 1);
}
__global__ void fill_edges(const int* __restrict__ src, const int* __restrict__ dst,
                           int* __restrict__ cursor, int* __restrict__ csr, int ne) {
  const int i = blockIdx.x * blockDim.x + threadIdx.x;
  if (i < ne) {
    const int p = atomicAdd(&cursor[dst[i]], 1);
    csr[p] = src[i];
  }
}
__global__ void alloc_ranges(const int* __restrict__ cnt, int* __restrict__ start,
                             int* __restrict__ cursor, int* __restrict__ total,
                             int* __restrict__ csr, int n) {
  const int i = blockIdx.x * blockDim.x + threadIdx.x;
  const int lane = threadIdx.x & 63;
  const int v = (i < n) ? cnt[i] : 0;
  int sc = v;
#pragma unroll
  for (int off = 1; off < 64; off <<= 1) {
    const int t = __shfl_up(sc, off);
    if (lane >= off) sc += t;
  }
  const int wtot = __shfl(sc, 63);
  int base = 0;
  if (lane == 63) base = atomicAdd(total, wtot);
  base = __shfl(base, 63);
  const int st = base + sc - v;
  if (i < n) {
    start[i] = st;
    cursor[i] = st + 1;
    csr[st] = i;  // self loop first
  }
}

// ---------------- GAT aggregate, layers 1-2 (f16 h) -------------------
// R19: TWO nodes per wave, interleaved. R18's 4-edge unroll was neutral
// because the serial chain is per-NODE (start/cnt -> csr idx -> gather,
// ~3 dependent misses ~= 2.7K cy), not per-edge. Interleaving two nodes
// doubles every level of the chain in flight per wave. Wave-uniform
// clamped indices + weight-zero selects keep control flow uniform when
// c0 != c1 (select AFTER fexp discards inf safely).
__global__ void gat_agg4(const _Float16* __restrict__ h,
                         const float* __restrict__ a_src,
                         const float* __restrict__ a_dst,
                         const int* __restrict__ start, const int* __restrict__ cnt,
                         const int* __restrict__ csr_src,
                         const float* __restrict__ bias,
                         _Float16* __restrict__ outH, int n_nodes) {
  const int gtid = blockIdx.x * blockDim.x + threadIdx.x;
  const int wid = gtid >> 6;
  const int lane = threadIdx.x & 63;
  const int n0 = wid * 2;
  if (n0 >= n_nodes) return;
  const int n1r = (n0 + 1 < n_nodes) ? (n0 + 1) : n0;
  const bool has1 = (n0 + 1 < n_nodes);
  const int ch = lane * 8;
  float as_r[8], ad_r[8];
#pragma unroll
  for (int j = 0; j < 8; ++j) {
    as_r[j] = a_src[ch + j];
    ad_r[j] = a_dst[ch + j];
  }
  const int s0 = start[n0], c0 = cnt[n0];
  const int s1 = start[n1r];
  const int c1 = has1 ? cnt[n1r] : 0;
  // self gathers for both nodes (csr[s]==node; gives dst-dot + self edge)
  const half8 vsA = *(const half8*)(h + (size_t)n0 * 512 + ch);
  const half8 vsB = *(const half8*)(h + (size_t)n1r * 512 + ch);
  float fsA[8], fsB[8];
  float tAs = 0.f, tAd = 0.f, tBs = 0.f, tBd = 0.f;
#pragma unroll
  for (int j = 0; j < 8; ++j) {
    fsA[j] = (float)vsA[j];
    fsB[j] = (float)vsB[j];
    tAs = fmaf(fsA[j], as_r[j], tAs);
    tAd = fmaf(fsA[j], ad_r[j], tAd);
    tBs = fmaf(fsB[j], as_r[j], tBs);
    tBd = fmaf(fsB[j], ad_r[j], tBd);
  }
#pragma unroll
  for (int off = 1; off < 16; off <<= 1) {
    tAs += __shfl_xor(tAs, off);
    tAd += __shfl_xor(tAd, off);
    tBs += __shfl_xor(tBs, off);
    tBd += __shfl_xor(tBd, off);
  }
  const float adA = tAd, adB = tBd;
  float eA = tAs + adA, eB = tBs + adB;
  eA = (eA > 0.f) ? eA : kNegSlope * eA;
  eB = (eB > 0.f) ? eB : kNegSlope * eB;
  const float wsA = fexp(eA);
  const float wsB = fexp(eB);
  float dA = wsA, dB = wsB;
  float aA[8], aB[8];
#pragma unroll
  for (int j = 0; j < 8; ++j) {
    aA[j] = wsA * fsA[j];
    aB[j] = wsB * fsB[j];
  }
  const int cm = (c0 > c1) ? c0 : c1;
  int i = 1;
  for (; i + 2 <= cm; i += 2) {
    const int jA0 = (i < c0) ? i : 0, jA1 = (i + 1 < c0) ? i + 1 : 0;
    const int jB0 = (i < c1) ? i : 0, jB1 = (i + 1 < c1) ? i + 1 : 0;
    const int sA0 = csr_src[s0 + jA0];
    const int sA1 = csr_src[s0 + jA1];
    const int sB0 = csr_src[s1 + jB0];
    const int sB1 = csr_src[s1 + jB1];
    const half8 vA0 = *(const half8*)(h + (size_t)sA0 * 512 + ch);
    const half8 vA1 = *(const half8*)(h + (size_t)sA1 * 512 + ch);
    const half8 vB0 = *(const half8*)(h + (size_t)sB0 * 512 + ch);
    const half8 vB1 = *(const half8*)(h + (size_t)sB1 * 512 + ch);
    float fA0[8], fA1[8], fB0[8], fB1[8];
    float tA0 = 0.f, tA1 = 0.f, tB0 = 0.f, tB1 = 0.f;
#pragma unroll
    for (int j = 0; j < 8; ++j) {
      fA0[j] = (float)vA0[j]; tA0 = fmaf(fA0[j], as_r[j], tA0);
      fA1[j] = (float)vA1[j]; tA1 = fmaf(fA1[j], as_r[j], tA1);
      fB0[j] = (float)vB0[j]; tB0 = fmaf(fB0[j], as_r[j], tB0);
      fB1[j] = (float)vB1[j]; tB1 = fmaf(fB1[j], as_r[j], tB1);
    }
#pragma unroll
    for (int off = 1; off < 16; off <<= 1) {
      tA0 += __shfl_xor(tA0, off);
      tA1 += __shfl_xor(tA1, off);
      tB0 += __shfl_xor(tB0, off);
      tB1 += __shfl_xor(tB1, off);
    }
    float eA0 = tA0 + adA, eA1 = tA1 + adA;
    float eB0 = tB0 + adB, eB1 = tB1 + adB;
    eA0 = (eA0 > 0.f) ? eA0 : kNegSlope * eA0;
    eA1 = (eA1 > 0.f) ? eA1 : kNegSlope * eA1;
    eB0 = (eB0 > 0.f) ? eB0 : kNegSlope * eB0;
    eB1 = (eB1 > 0.f) ? eB1 : kNegSlope * eB1;
    const float wA0 = (i < c0) ? fexp(eA0) : 0.f;
    const float wA1 = (i + 1 < c0) ? fexp(eA1) : 0.f;
    const float wB0 = (i < c1) ? fexp(eB0) : 0.f;
    const float wB1 = (i + 1 < c1) ? fexp(eB1) : 0.f;
    dA += wA0 + wA1;
    dB += wB0 + wB1;
#pragma unroll
    for (int j = 0; j < 8; ++j) {
      aA[j] = fmaf(wA0, fA0[j], aA[j]);
      aA[j] = fmaf(wA1, fA1[j], aA[j]);
      aB[j] = fmaf(wB0, fB0[j], aB[j]);
      aB[j] = fmaf(wB1, fB1[j], aB[j]);
    }
  }
  if (i < cm) {  // tail: at most one edge per node
    const int jA = (i < c0) ? i : 0;
    const int jB = (i < c1) ? i : 0;
    const int sA = csr_src[s0 + jA];
    const int sB = csr_src[s1 + jB];
    const half8 vA = *(const half8*)(h + (size_t)sA * 512 + ch);
    const half8 vB = *(const half8*)(h + (size_t)sB * 512 + ch);
    float fA[8], fB[8];
    float tA = 0.f, tB = 0.f;
#pragma unroll
    for (int j = 0; j < 8; ++j) {
      fA[j] = (float)vA[j]; tA = fmaf(fA[j], as_r[j], tA);
      fB[j] = (float)vB[j]; tB = fmaf(fB[j], as_r[j], tB);
    }
#pragma unroll
    for (int off = 1; off < 16; off <<= 1) {
      tA += __shfl_xor(tA, off);
      tB += __shfl_xor(tB, off);
    }
    float eA2 = tA + adA, eB2 = tB + adB;
    eA2 = (eA2 > 0.f) ? eA2 : kNegSlope * eA2;
    eB2 = (eB2 > 0.f) ? eB2 : kNegSlope * eB2;
    const float wA = (i < c0) ? fexp(eA2) : 0.f;
    const float wB = (i < c1) ? fexp(eB2) : 0.f;
    dA += wA;
    dB += wB;
#pragma unroll
    for (int j = 0; j < 8; ++j) {
      aA[j] = fmaf(wA, fA[j], aA[j]);
      aB[j] = fmaf(wB, fB[j], aB[j]);
    }
  }
  const float invA = 1.f / (dA + 1e-16f);
  const float invB = 1.f / (dB + 1e-16f);
  half8 HA, HB;
#pragma unroll
  for (int j = 0; j < 8; ++j) {
    float vA = aA[j] * invA + bias[ch + j];
    vA = (vA > 0.f) ? vA : (fexp(vA) - 1.f);  // elu via hw exp
    HA[j] = (_Float16)vA;
    float vB = aB[j] * invB + bias[ch + j];
    vB = (vB > 0.f) ? vB : (fexp(vB) - 1.f);
    HB[j] = (_Float16)vB;
  }
  *(half8*)(outH + (size_t)n0 * 512 + ch) = HA;
  if (has1) *(half8*)(outH + (size_t)n1r * 512 + ch) = HB;
}

// ---------- GAT aggregate, layer 3 (H=1, f16 h, 2 nodes/wave) ---------
__global__ void gat_agg_l3(const _Float16* __restrict__ h,
                           const float* __restrict__ a_src,
                           const float* __restrict__ a_dst,
                           const int* __restrict__ start, const int* __restrict__ cnt,
                           const int* __restrict__ csr_src,
                           const float* __restrict__ bias,
                           float* __restrict__ out, int n_nodes) {
  const int gtid = blockIdx.x * blockDim.x + threadIdx.x;
  const int wid = gtid >> 6;
  const int lane = threadIdx.x & 63;
  const int n0 = wid * 2;
  if (n0 >= n_nodes) return;
  const int n1r = (n0 + 1 < n_nodes) ? (n0 + 1) : n0;
  const bool has1 = (n0 + 1 < n_nodes);
  const float2 asv = *(const float2*)(a_src + lane * 2);
  const float2 adv = *(const float2*)(a_dst + lane * 2);
  const int s0 = start[n0], c0 = cnt[n0];
  const int s1 = start[n1r];
  const int c1 = has1 ? cnt[n1r] : 0;
  // self gathers
  const half2v vsA = *(const half2v*)(h + (size_t)n0 * 128 + lane * 2);
  const half2v vsB = *(const half2v*)(h + (size_t)n1r * 128 + lane * 2);
  const float xA = (float)vsA[0], yA = (float)vsA[1];
  const float xB = (float)vsB[0], yB = (float)vsB[1];
  float tAs = fmaf(xA, asv.x, yA * asv.y);
  float tAd = fmaf(xA, adv.x, yA * adv.y);
  float tBs = fmaf(xB, asv.x, yB * asv.y);
  float tBd = fmaf(xB, adv.x, yB * adv.y);
#pragma unroll
  for (int off = 1; off < 64; off <<= 1) {
    tAs += __shfl_xor(tAs, off);
    tAd += __shfl_xor(tAd, off);
    tBs += __shfl_xor(tBs, off);
    tBd += __shfl_xor(tBd, off);
  }
  const float adA = tAd, adB = tBd;
  float eA = tAs + adA, eB = tBs + adB;
  eA = (eA > 0.f) ? eA : kNegSlope * eA;
  eB = (eB > 0.f) ? eB : kNegSlope * eB;
  const float wsA = fexp(eA);
  const float wsB = fexp(eB);
  float dA = wsA, dB = wsB;
  float2 aA = make_float2(wsA * xA, wsA * yA);
  float2 aB = make_float2(wsB * xB, wsB * yB);
  const int cm = (c0 > c1) ? c0 : c1;
  int i = 1;
  for (; i + 2 <= cm; i += 2) {
    const int jA0 = (i < c0) ? i : 0, jA1 = (i + 1 < c0) ? i + 1 : 0;
    const int jB0 = (i < c1) ? i : 0, jB1 = (i + 1 < c1) ? i + 1 : 0;
    const int sA0 = csr_src[s0 + jA0];
    const int sA1 = csr_src[s0 + jA1];
    const int sB0 = csr_src[s1 + jB0];
    const int sB1 = csr_src[s1 + jB1];
    const half2v vA0 = *(const half2v*)(h + (size_t)sA0 * 128 + lane * 2);
    const half2v vA1 = *(const half2v*)(h + (size_t)sA1 * 128 + lane * 2);
    const half2v vB0 = *(const half2v*)(h + (size_t)sB0 * 128 + lane * 2);
    const half2v vB1 = *(const half2v*)(h + (size_t)sB1 * 128 + lane * 2);
    const float xA0 = (float)vA0[0], yA0 = (float)vA0[1];
    const float xA1 = (float)vA1[0], yA1 = (float)vA1[1];
    const float xB0 = (float)vB0[0], yB0 = (float)vB0[1];
    const float xB1 = (float)vB1[0], yB1 = (float)vB1[1];
    float tA0 = fmaf(xA0, asv.x, yA0 * asv.y);
    float tA1 = fmaf(xA1, asv.x, yA1 * asv.y);
    float tB0 = fmaf(xB0, asv.x, yB0 * asv.y);
    float tB1 = fmaf(xB1, asv.x, yB1 * asv.y);
#pragma unroll
    for (int off = 1; off < 64; off <<= 1) {
      tA0 += __shfl_xor(tA0, off);
      tA1 += __shfl_xor(tA1, off);
      tB0 += __shfl_xor(tB0, off);
      tB1 += __shfl_xor(tB1, off);
    }
    float eA0 = tA0 + adA, eA1 = tA1 + adA;
    float eB0 = tB0 + adB, eB1 = tB1 + adB;
    eA0 = (eA0 > 0.f) ? eA0 : kNegSlope * eA0;
    eA1 = (eA1 > 0.f) ? eA1 : kNegSlope * eA1;
    eB0 = (eB0 > 0.f) ? eB0 : kNegSlope * eB0;
    eB1 = (eB1 > 0.f) ? eB1 : kNegSlope * eB1;
    const float wA0 = (i < c0) ? fexp(eA0) : 0.f;
    const float wA1 = (i + 1 < c0) ? fexp(eA1) : 0.f;
    const float wB0 = (i < c1) ? fexp(eB0) : 0.f;
    const float wB1 = (i + 1 < c1) ? fexp(eB1) : 0.f;
    dA += wA0 + wA1;
    dB += wB0 + wB1;
    aA.x = fmaf(wA0, xA0, aA.x); aA.x = fmaf(wA1, xA1, aA.x);
    aA.y = fmaf(wA0, yA0, aA.y); aA.y = fmaf(wA1, yA1, aA.y);
    aB.x = fmaf(wB0, xB0, aB.x); aB.x = fmaf(wB1, xB1, aB.x);
    aB.y = fmaf(wB0, yB0, aB.y); aB.y = fmaf(wB1, yB1, aB.y);
  }
  if (i < cm) {
    const int jA = (i < c0) ? i : 0;
    const int jB = (i < c1) ? i : 0;
    const int sA = csr_src[s0 + jA];
    const int sB = csr_src[s1 + jB];
    const half2v vA = *(const half2v*)(h + (size_t)sA * 128 + lane * 2);
    const half2v vB = *(const half2v*)(h + (size_t)sB * 128 + lane * 2);
    const float xA2 = (float)vA[0], yA2 = (float)vA[1];
    const float xB2 = (float)vB[0], yB2 = (float)vB[1];
    float tA = fmaf(xA2, asv.x, yA2 * asv.y);
    float tB = fmaf(xB2, asv.x, yB2 * asv.y);
#pragma unroll
    for (int off = 1; off < 64; off <<= 1) {
      tA += __shfl_xor(tA, off);
      tB += __shfl_xor(tB, off);
    }
    float eA2 = tA + adA, eB2 = tB + adB;
    eA2 = (eA2 > 0.f) ? eA2 : kNegSlope * eA2;
    eB2 = (eB2 > 0.f) ? eB2 : kNegSlope * eB2;
    const float wA = (i < c0) ? fexp(eA2) : 0.f;
    const float wB = (i < c1) ? fexp(eB2) : 0.f;
    dA += wA;
    dB += wB;
    aA.x = fmaf(wA, xA2, aA.x);
    aA.y = fmaf(wA, yA2, aA.y);
    aB.x = fmaf(wB, xB2, aB.x);
    aB.y = fmaf(wB, yB2, aB.y);
  }
  const float invA = 1.f / (dA + 1e-16f);
  const float invB = 1.f / (dB + 1e-16f);
  *(float2*)(out + (size_t)n0 * 128 + lane * 2) =
      make_float2(aA.x * invA + bias[lane * 2],
                  aA.y * invA + bias[lane * 2 + 1]);
  if (has1)
    *(float2*)(out + (size_t)n1r * 128 + lane * 2) =
        make_float2(aB.x * invB + bias[lane * 2],
                    aB.y * invB + bias[lane * 2 + 1]);
}

// ------- global max pool over sorted batch (both encoders, 1 launch) ---
__global__ void pool_max2(const float* __restrict__ x, const int* __restrict__ bt1,
                          const int* __restrict__ bt2, float* __restrict__ emb) {
  __shared__ int lohi[2];
  const int enc = blockIdx.x >> 8;
  const int g = blockIdx.x & 255;
  const int* batch = enc ? bt2 : bt1;
  const float* xx = x + (size_t)enc * kN * 128;
  if (threadIdx.x == 0) {
    int lo = 0, hi = kN;
    while (lo < hi) {
      const int mid = (lo + hi) >> 1;
      if (batch[mid] < g) lo = mid + 1; else hi = mid;
    }
    lohi[0] = lo;
    hi = kN;
    while (lo < hi) {
      const int mid = (lo + hi) >> 1;
      if (batch[mid] < g + 1) lo = mid + 1; else hi = mid;
    }
    lohi[1] = lo;
  }
  __syncthreads();
  const int lo = lohi[0], hi = lohi[1];
  const int c = threadIdx.x;  // 128 channels
  float m = -1e30f;
  for (int nid = lo; nid < hi; ++nid) m = fmaxf(m, xx[(size_t)nid * 128 + c]);
  emb[(size_t)blockIdx.x * 128 + c] = (lo < hi) ? m : 0.f;
}
// ------- single-encoder pool (fallback path) --------------------------
__global__ void pool_max(const float* __restrict__ x, const int* __restrict__ batch,
                         float* __restrict__ emb, int n_nodes) {
  __shared__ int lohi[2];
  const int g = blockIdx.x;
  if (threadIdx.x == 0) {
    int lo = 0, hi = n_nodes;
    while (lo < hi) {
      const int mid = (lo + hi) >> 1;
      if (batch[mid] < g) lo = mid + 1; else hi = mid;
    }
    lohi[0] = lo;
    hi = n_nodes;
    while (lo < hi) {
      const int mid = (lo + hi) >> 1;
      if (batch[mid] < g + 1) lo = mid + 1; else hi = mid;
    }
    lohi[1] = lo;
  }
  __syncthreads();
  const int lo = lohi[0], hi = lohi[1];
  const int c = threadIdx.x;  // 128 channels
  float m = -1e30f;
  for (int nid = lo; nid < hi; ++nid) m = fmaxf(m, x[(size_t)nid * 128 + c]);
  emb[g * 128 + c] = (lo < hi) ? m : 0.f;
}

// ---------------- final MLP head --------------------------------------
__global__ void mlp_head(const float* __restrict__ e1, const float* __restrict__ e2,
                         const float* __restrict__ mw1, const float* __restrict__ mb1,
                         const float* __restrict__ mw2, const float* __restrict__ mb2,
                         float* __restrict__ out) {
  __shared__ float z[256];
  __shared__ float red[128];
  const int g = blockIdx.x;
  const int j = threadIdx.x;  // 128
  z[j] = e1[g * 128 + j];
  z[j + 128] = e2[g * 128 + j];
  __syncthreads();
  float acc = mb1[j];
  for (int k = 0; k < 256; ++k) acc = fmaf(z[k], mw1[k * 128 + j], acc);
  acc = fmaxf(acc, 0.f) * mw2[j];
  red[j] = acc;
  __syncthreads();
  for (int s = 64; s > 0; s >>= 1) {
    if (j < s) red[j] += red[j + s];
    __syncthreads();
  }
  if (j == 0) out[g] = red[0] + mb2[0];
}

// ---------------- launcher --------------------------------------------
namespace {
struct Bufs {
  _Float16 *R1h, *R2h;
  float *R1f, *R2f, *asrc, *adst;
  int *cnt, *start, *cursor, *csr, *total;
  _Float16 *Wth1, *Wth2, *Wth3;
  float* emb;
  size_t need;
};

Bufs plan(void* d_ws, int M, int E) {
  Bufs b;
  char* w = (char*)d_ws;
  size_t off = 0;
  auto take = [&](size_t bytes) -> void* {
    void* p = w + off;
    off += (bytes + 255) & ~(size_t)255;
    return p;
  };
  b.R1h = (_Float16*)take((size_t)M * 512 * 2);  // f16 activations
  b.R1f = (float*)b.R1h;                         // layer-3 out alias [M,128]
  b.R2h = (_Float16*)take((size_t)M * 512 * 2);  // h f16 (l3 h f16 [M,128])
  b.R2f = (float*)b.R2h;
  b.asrc = (float*)take((size_t)M * 4 * 4);      // (kept for ws layout stability)
  b.adst = (float*)take((size_t)M * 4 * 4);
  b.cnt = (int*)take((size_t)M * 4);
  b.start = (int*)take((size_t)M * 4);
  b.cursor = (int*)take((size_t)M * 4);
  b.csr = (int*)take((size_t)E * 4);
  b.total = (int*)take(256);
  b.Wth1 = (_Float16*)take((size_t)64 * 512 * 2);
  b.Wth2 = (_Float16*)take((size_t)512 * 512 * 2);
  b.Wth3 = (_Float16*)take((size_t)512 * 128 * 2);
  b.emb = (float*)take((size_t)2 * kG * 128 * 4);
  b.need = off;
  return b;
}

void run_layers(const Bufs& b, void* const* d_in, int M, hipStream_t stream) {
  const float* as1 = (const float*)d_in[7];
  const float* ad1 = (const float*)d_in[8];
  const float* b1 = (const float*)d_in[9];
  const float* as2 = (const float*)d_in[11];
  const float* ad2 = (const float*)d_in[12];
  const float* b2 = (const float*)d_in[13];
  const float* as3 = (const float*)d_in[15];
  const float* ad3 = (const float*)d_in[16];
  const float* b3 = (const float*)d_in[17];
  const int aggBlocks = (((M + 1) / 2) * 64 + 255) / 256;  // 2 nodes/wave
  const int MT = (M + 255) / 256;         // 256-row tiles
  const int SP = (MT + 7) / 8;            // row-tile groups of 8 (XCD map)

  // layer 1: [M,64] @ [64,512], h -> f16 (A1h aliases R1h)
  gemm_ring<1, 256, 2><<<SP * 16, 512, 0, stream>>>(b.R1h, b.Wth1, b.R2h, M, 512, 64);
  gat_agg4<<<aggBlocks, 256, 0, stream>>>(b.R2h, as1, ad1, b.start, b.cnt,
                                          b.csr, b1, b.R1h, M);
  // layer 2: [M,512] @ [512,512], h -> f16
  gemm_ring<1, 256, 2><<<SP * 16, 512, 0, stream>>>(b.R1h, b.Wth2, b.R2h, M, 512, 512);
  gat_agg4<<<aggBlocks, 256, 0, stream>>>(b.R2h, as2, ad2, b.start, b.cnt,
                                          b.csr, b2, b.R1h, M);
  // layer 3: [M,512] @ [512,128], H=1, no elu, h -> f16
  gemm_ring<1, 128, 1><<<SP * 8, 512, 0, stream>>>(b.R1h, b.Wth3, b.R2h, M, 128, 512);
  gat_agg_l3<<<aggBlocks, 256, 0, stream>>>(b.R2h, as3, ad3, b.start, b.cnt,
                                            b.csr, b3, b.R1f, M);
}
}  // namespace

extern "C" void kernel_launch(void* const* d_in, const int* in_sizes, int n_in,
                              void* d_out, int out_size, void* d_ws, size_t ws_size,
                              hipStream_t stream) {
  (void)in_sizes; (void)n_in; (void)out_size;
  const float* W1 = (const float*)d_in[6];
  const float* W2 = (const float*)d_in[10];
  const float* W3 = (const float*)d_in[14];
  const float* mw1 = (const float*)d_in[18];
  const float* mb1 = (const float*)d_in[19];
  const float* mw2 = (const float*)d_in[20];
  const float* mb2 = (const float*)d_in[21];

  // Prefer combined (both encoders batched, M=2N) if it fits the workspace.
  Bufs bc = plan(d_ws, 2 * kN, 2 * kE2);
  const bool combined = bc.need <= ws_size;
  Bufs b = combined ? bc : plan(d_ws, kN, kE2);

  const int wtot = 64 * 512 + 512 * 512 + 512 * 128;
  if (combined) {
    const int M = 2 * kN;
    const int* ei0 = (const int*)d_in[1];
    const int* ei1 = (const int*)d_in[4];
    prep_all<<<(M * 64 + wtot + 255) / 256, 256, 0, stream>>>(
        (const float*)d_in[0], (const float*)d_in[3], b.R1h, b.cnt, b.total,
        W1, b.Wth1, W2, b.Wth2, W3, b.Wth3);
    count_edges2<<<(2 * kE + 255) / 256, 256, 0, stream>>>(ei0 + kE, ei1 + kE,
                                                           b.cnt);
    alloc_ranges<<<(M + 255) / 256, 256, 0, stream>>>(b.cnt, b.start, b.cursor,
                                                      b.total, b.csr, M);
    fill_edges2<<<(2 * kE + 255) / 256, 256, 0, stream>>>(ei0, ei0 + kE, ei1,
                                                          ei1 + kE, b.cursor, b.csr);
    run_layers(b, d_in, M, stream);
    pool_max2<<<2 * kG, 128, 0, stream>>>(b.R1f, (const int*)d_in[2],
                                          (const int*)d_in[5], b.emb);
  } else {
    wt_split_all<<<(wtot + 255) / 256, 256, 0, stream>>>(W1, b.Wth1, W2, b.Wth2,
                                                         W3, b.Wth3);
    for (int enc = 0; enc < 2; ++enc) {
      const float* x = (const float*)d_in[enc * 3 + 0];
      const int* ei = (const int*)d_in[enc * 3 + 1];
      const int* batch = (const int*)d_in[enc * 3 + 2];
      prep<<<(kN * 64 + 255) / 256, 256, 0, stream>>>(x, b.R1h, b.cnt, b.total,
                                                      kN * 64, kN);
      count_edges<<<(kE + 255) / 256, 256, 0, stream>>>(ei + kE, b.cnt, kE);
      alloc_ranges<<<(kN + 255) / 256, 256, 0, stream>>>(b.cnt, b.start, b.cursor,
                                                         b.total, b.csr, kN);
      fill_edges<<<(kE + 255) / 256, 256, 0, stream>>>(ei, ei + kE, b.cursor, b.csr,
                                                       kE);
      run_layers(b, d_in, kN, stream);
      pool_max<<<kG, 128, 0, stream>>>(b.R1f, batch, b.emb + (size_t)enc * kG * 128,
                                       kN);
    }
  }
  mlp_head<<<kG, 128, 0, stream>>>(b.emb, b.emb + (size_t)kG * 128, mw1, mb1, mw2,
                                   mb2, (float*)d_out);
}

// Round 8
// 635.347 us; speedup vs baseline: 1.3337x; 1.0113x over previous
//
#include <hip/hip_runtime.h>
#include <cstdint>

namespace {
constexpr int kN = 50000;          // nodes per encoder
constexpr int kE = 200000;         // directed edges per encoder (pre self-loop)
constexpr int kE2 = kE + kN;       // with self loops (per encoder)
constexpr int kG = 256;            // graphs per encoder
constexpr float kNegSlope = 0.2f;
}

using half8   = __attribute__((ext_vector_type(8))) _Float16;
using half2v  = __attribute__((ext_vector_type(2))) _Float16;
using floatx4 = __attribute__((ext_vector_type(4))) float;

__device__ __forceinline__ void gld_lds16(const void* g, void* l) {
  __builtin_amdgcn_global_load_lds(
      (const __attribute__((address_space(1))) unsigned int*)g,
      (__attribute__((address_space(3))) unsigned int*)l, 16, 0, 0);
}

// fast exp: e^x = 2^(x*log2(e)) via hardware v_exp_f32 (no libm call)
__device__ __forceinline__ float fexp(float x) {
  return __builtin_amdgcn_exp2f(x * 1.44269504088896f);
}

// ---------------- fp16 MFMA GEMM: C[M,N] = A[M,K] @ B[K,N] -----------
// R20: SINGLE-barrier ring. R15's ring had 2 barriers/K-tile (32
// convergences/block); at 1 block/CU (128KB LDS) there is no inter-block
// overlap, so every convergence pays the slowest wave's jitter — the
// profile showed MfmaUtil 21% with no BW limit (HBM 1.6, staged 4.1,
// LDS 26 B/cy/CU — all under ceilings). With a 4-slot distance-3 ring,
// ONE barrier per tile is sufficient: a wave passes barrier kt only
// after all waves consumed tile kt-1's fragments (MFMA issue forces the
// ds_read data into regs first), so staging kt+3 -> slot[(kt-1)&3]
// AFTER the barrier can never overwrite live data. Counted wait is
// vmcnt(2*LPT): outstanding = tiles kt,kt+1,kt+2 at wait time.
template <int OUTF16, int BN, int CT>
__global__ __launch_bounds__(512, 2) void gemm_ring(
    const _Float16* __restrict__ A, const _Float16* __restrict__ B,
    void* __restrict__ Cv, int M, int N, int K) {
  constexpr int ASL = 1024;                // A slots/tile (256 rows x 32k x 2B /16)
  constexpr int BSL = BN * 4;              // B slots/tile (1024 or 512)
  constexpr int SLOT = (ASL + BSL) * 16;   // 32KB or 24KB
  constexpr int LPT = (ASL + BSL) / 512;   // loads/thread/tile: 4 or 3
  constexpr int WN = (BN == 256) ? 4 : 2;  // waves along N
  constexpr int WM = 8 / WN;
  constexpr int WTM = 256 / WM;            // 128 or 64
  constexpr int WTN = BN / WN;             // 64
  constexpr int MI = WTM / 16;             // 8 or 4
  constexpr int NI = WTN / 16;             // 4
  __shared__ alignas(16) char smem[4 * SLOT];  // 128KB or 96KB ring
  const int t = threadIdx.x;
  const int w = t >> 6, l = t & 63;
  const int x = blockIdx.x & 7, s = blockIdx.x >> 3;
  const int col = (CT == 1) ? 0 : (s & (CT - 1));
  const int rt = ((CT == 1) ? s : (s >> 1)) * 8 + x;
  const int bm = rt * 256;
  const int bn = col * BN;
  if (bm >= M) return;  // padded row-tiles: whole block exits (no barrier)
  const int wr = w / WN, wc = w % WN;
  const int quad = l >> 4, lrow = l & 15;

  floatx4 acc[MI][NI];
#pragma unroll
  for (int mi = 0; mi < MI; ++mi)
#pragma unroll
    for (int ni = 0; ni < NI; ++ni) acc[mi][ni] = (floatx4){0.f, 0.f, 0.f, 0.f};

  // stage tile kt's A-part (2 loads) / B-part (LPT-2 loads) into ring slot
  auto stageA = [&](int kt) {
    char* buf = smem + (size_t)(kt & 3) * SLOT;
    int k0 = kt * 32;
    k0 = (k0 > K - 32) ? (K - 32) : k0;  // clamp: beyond-NT garbage stays in-bounds
#pragma unroll
    for (int i = 0; i < 2; ++i) {
      const int sl = i * 512 + t;
      const int row = ((sl >> 6) << 4) + (sl & 15);
      const int q = (sl >> 4) & 3;
      int ga = bm + row;
      ga = (ga < M) ? ga : (M - 1);      // clamp: keep lanes active
      gld_lds16(A + (size_t)ga * K + k0 + q * 8, buf + sl * 16);
    }
  };
  auto stageB = [&](int kt) {
    char* buf = smem + (size_t)(kt & 3) * SLOT + ASL * 16;
    int k0 = kt * 32;
    k0 = (k0 > K - 32) ? (K - 32) : k0;
#pragma unroll
    for (int i = 0; i < LPT - 2; ++i) {
      const int sl = i * 512 + t;
      const int row = ((sl >> 6) << 4) + (sl & 15);
      const int q = (sl >> 4) & 3;
      gld_lds16(B + (size_t)(bn + row) * K + k0 + q * 8, buf + sl * 16);
    }
  };

  // prologue: tiles 0,1,2 in flight (3*LPT loads)
  stageA(0); stageB(0);
  stageA(1); stageB(1);
  stageA(2); stageB(2);

  const int NT = K >> 5;
  for (int kt = 0; kt < NT; ++kt) {
    char* bufc = smem + (size_t)(kt & 3) * SLOT;
    // outstanding: tiles kt,kt+1,kt+2 (3*LPT). Wait for tile kt's LPT.
    if constexpr (LPT == 4)
      asm volatile("s_waitcnt vmcnt(8)" ::: "memory");
    else
      asm volatile("s_waitcnt vmcnt(6)" ::: "memory");
    __builtin_amdgcn_s_barrier();  // all waves: slot[kt] ready AND slot[kt-1] consumed
    asm volatile("" ::: "memory");
    stageA(kt + 3);                // -> slot[(kt-1)&3], safe after barrier
    half8 fa[MI], fb[NI];
#pragma unroll
    for (int ni = 0; ni < NI; ++ni)
      fb[ni] = *(const half8*)(bufc + ASL * 16 + ((wc * NI + ni) << 10) + l * 16);
#pragma unroll
    for (int mi = 0; mi < MI / 2; ++mi)
      fa[mi] = *(const half8*)(bufc + ((wr * MI + mi) << 10) + l * 16);
    __builtin_amdgcn_s_setprio(1);
#pragma unroll
    for (int mi = 0; mi < MI / 2; ++mi)
#pragma unroll
      for (int ni = 0; ni < NI; ++ni)
        acc[mi][ni] = __builtin_amdgcn_mfma_f32_16x16x32_f16(
            fa[mi], fb[ni], acc[mi][ni], 0, 0, 0);
    __builtin_amdgcn_s_setprio(0);
    stageB(kt + 3);                // remaining loads of tile kt+3
#pragma unroll
    for (int mi = MI / 2; mi < MI; ++mi)
      fa[mi] = *(const half8*)(bufc + ((wr * MI + mi) << 10) + l * 16);
    __builtin_amdgcn_s_setprio(1);
#pragma unroll
    for (int mi = MI / 2; mi < MI; ++mi)
#pragma unroll
      for (int ni = 0; ni < NI; ++ni)
        acc[mi][ni] = __builtin_amdgcn_mfma_f32_16x16x32_f16(
            fa[mi], fb[ni], acc[mi][ni], 0, 0, 0);
    __builtin_amdgcn_s_setprio(0);
    // no end-of-tile barrier: distance-3 ring tolerates 1-iteration drift
  }
  asm volatile("s_waitcnt vmcnt(0)" ::: "memory");  // drain garbage prefetches
  // epilogue: C/D layout col=lane&15, row=quad*4+reg
  const int colbase = bn + wc * WTN + lrow;
#pragma unroll
  for (int mi = 0; mi < MI; ++mi) {
    const int rbase = bm + wr * WTM + mi * 16 + quad * 4;
#pragma unroll
    for (int r = 0; r < 4; ++r) {
      const int grow = rbase + r;
      if (grow < M) {
        if constexpr (OUTF16) {
          _Float16* C = (_Float16*)Cv;
#pragma unroll
          for (int ni = 0; ni < NI; ++ni)
            C[(size_t)grow * N + colbase + ni * 16] = (_Float16)acc[mi][ni][r];
        } else {
          float* C = (float*)Cv;
#pragma unroll
          for (int ni = 0; ni < NI; ++ni)
            C[(size_t)grow * N + colbase + ni * 16] = acc[mi][ni][r];
        }
      }
    }
  }
}

// ------- all three weight transposes + f16 casts (fallback path) ------
__global__ void wt_split_all(const float* __restrict__ W1, _Float16* Th1,
                             const float* __restrict__ W2, _Float16* Th2,
                             const float* __restrict__ W3, _Float16* Th3) {
  int idx = blockIdx.x * blockDim.x + threadIdx.x;
  const float* W;
  _Float16* Th;
  int K, N;
  if (idx < 64 * 512) {
    W = W1; Th = Th1; K = 64; N = 512;
  } else if (idx < 64 * 512 + 512 * 512) {
    idx -= 64 * 512;
    W = W2; Th = Th2; K = 512; N = 512;
  } else if (idx < 64 * 512 + 512 * 512 + 512 * 128) {
    idx -= 64 * 512 + 512 * 512;
    W = W3; Th = Th3; K = 512; N = 128;
  } else {
    return;
  }
  const int k = idx / N;
  const int n = idx - k * N;
  Th[n * K + k] = (_Float16)W[idx];
}

// --- combined prep: x casts + cnt=1 + total=0 + weight transposes -----
__global__ void prep_all(const float* __restrict__ x0, const float* __restrict__ x1,
                         _Float16* __restrict__ Xh, int* __restrict__ cnt,
                         int* __restrict__ total,
                         const float* __restrict__ W1, _Float16* Th1,
                         const float* __restrict__ W2, _Float16* Th2,
                         const float* __restrict__ W3, _Float16* Th3) {
  const int idx = blockIdx.x * blockDim.x + threadIdx.x;
  const int half = kN * 64;
  if (idx < half) {
    Xh[idx] = (_Float16)x0[idx];
  } else if (idx < 2 * half) {
    Xh[idx] = (_Float16)x1[idx - half];
  } else {
    int e = idx - 2 * half;
    const float* W;
    _Float16* Th;
    int K, N;
    if (e < 64 * 512) {
      W = W1; Th = Th1; K = 64; N = 512;
    } else if (e < 64 * 512 + 512 * 512) {
      e -= 64 * 512;
      W = W2; Th = Th2; K = 512; N = 512;
    } else if (e < 64 * 512 + 512 * 512 + 512 * 128) {
      e -= 64 * 512 + 512 * 512;
      W = W3; Th = Th3; K = 512; N = 128;
    } else {
      W = nullptr; Th = nullptr; K = N = 0;
    }
    if (W) {
      const int k = e / N;
      const int n = e - k * N;
      Th[n * K + k] = (_Float16)W[e];
    }
  }
  if (idx < 2 * kN) cnt[idx] = 1;  // the self loop
  if (idx == 0) *total = 0;
}
// ------- single-encoder prep (fallback path) --------------------------
__global__ void prep(const float* __restrict__ X, _Float16* __restrict__ Xh,
                     int* __restrict__ cnt, int* __restrict__ total, int nsplit,
                     int n) {
  const int idx = blockIdx.x * blockDim.x + threadIdx.x;
  if (idx < nsplit) Xh[idx] = (_Float16)X[idx];
  if (idx < n) cnt[idx] = 1;
  if (idx == 0) *total = 0;
}

// ---------------- CSR (by dst) build ----------------------------------
__global__ void count_edges2(const int* __restrict__ d0, const int* __restrict__ d1,
                             int* __restrict__ cnt) {
  const int i = blockIdx.x * blockDim.x + threadIdx.x;
  if (i < kE) atomicAdd(&cnt[d0[i]], 1);
  else if (i < 2 * kE) atomicAdd(&cnt[d1[i - kE] + kN], 1);
}
__global__ void fill_edges2(const int* __restrict__ s0, const int* __restrict__ d0,
                            const int* __restrict__ s1, const int* __restrict__ d1,
                            int* __restrict__ cursor, int* __restrict__ csr) {
  const int i = blockIdx.x * blockDim.x + threadIdx.x;
  if (i < kE) {
    const int p = atomicAdd(&cursor[d0[i]], 1);
    csr[p] = s0[i];
  } else if (i < 2 * kE) {
    const int j = i - kE;
    const int p = atomicAdd(&cursor[d1[j] + kN], 1);
    csr[p] = s1[j] + kN;
  }
}
__global__ void count_edges(const int* __restrict__ dst, int* __restrict__ cnt,
                            int ne) {
  const int i = blockIdx.x * blockDim.x + threadIdx.x;
  if (i < ne) atomicAdd(&cnt[dst[i]], 1);
}
__global__ void fill_edges(const int* __restrict__ src, const int* __restrict__ dst,
                           int* __restrict__ cursor, int* __restrict__ csr, int ne) {
  const int i = blockIdx.x * blockDim.x + threadIdx.x;
  if (i < ne) {
    const int p = atomicAdd(&cursor[dst[i]], 1);
    csr[p] = src[i];
  }
}
__global__ void alloc_ranges(const int* __restrict__ cnt, int* __restrict__ start,
                             int* __restrict__ cursor, int* __restrict__ total,
                             int* __restrict__ csr, int n) {
  const int i = blockIdx.x * blockDim.x + threadIdx.x;
  const int lane = threadIdx.x & 63;
  const int v = (i < n) ? cnt[i] : 0;
  int sc = v;
#pragma unroll
  for (int off = 1; off < 64; off <<= 1) {
    const int t = __shfl_up(sc, off);
    if (lane >= off) sc += t;
  }
  const int wtot = __shfl(sc, 63);
  int base = 0;
  if (lane == 63) base = atomicAdd(total, wtot);
  base = __shfl(base, 63);
  const int st = base + sc - v;
  if (i < n) {
    start[i] = st;
    cursor[i] = st + 1;
    csr[st] = i;  // self loop first
  }
}

// ---------------- GAT aggregate, layers 1-2 (f16 h) -------------------
// R19: TWO nodes per wave, interleaved — the serial chain is per-NODE
// (start/cnt -> csr idx -> gather, ~3 dependent misses); interleaving
// two nodes doubles every level of the chain in flight per wave.
__global__ void gat_agg4(const _Float16* __restrict__ h,
                         const float* __restrict__ a_src,
                         const float* __restrict__ a_dst,
                         const int* __restrict__ start, const int* __restrict__ cnt,
                         const int* __restrict__ csr_src,
                         const float* __restrict__ bias,
                         _Float16* __restrict__ outH, int n_nodes) {
  const int gtid = blockIdx.x * blockDim.x + threadIdx.x;
  const int wid = gtid >> 6;
  const int lane = threadIdx.x & 63;
  const int n0 = wid * 2;
  if (n0 >= n_nodes) return;
  const int n1r = (n0 + 1 < n_nodes) ? (n0 + 1) : n0;
  const bool has1 = (n0 + 1 < n_nodes);
  const int ch = lane * 8;
  float as_r[8], ad_r[8];
#pragma unroll
  for (int j = 0; j < 8; ++j) {
    as_r[j] = a_src[ch + j];
    ad_r[j] = a_dst[ch + j];
  }
  const int s0 = start[n0], c0 = cnt[n0];
  const int s1 = start[n1r];
  const int c1 = has1 ? cnt[n1r] : 0;
  // self gathers for both nodes (csr[s]==node; gives dst-dot + self edge)
  const half8 vsA = *(const half8*)(h + (size_t)n0 * 512 + ch);
  const half8 vsB = *(const half8*)(h + (size_t)n1r * 512 + ch);
  float fsA[8], fsB[8];
  float tAs = 0.f, tAd = 0.f, tBs = 0.f, tBd = 0.f;
#pragma unroll
  for (int j = 0; j < 8; ++j) {
    fsA[j] = (float)vsA[j];
    fsB[j] = (float)vsB[j];
    tAs = fmaf(fsA[j], as_r[j], tAs);
    tAd = fmaf(fsA[j], ad_r[j], tAd);
    tBs = fmaf(fsB[j], as_r[j], tBs);
    tBd = fmaf(fsB[j], ad_r[j], tBd);
  }
#pragma unroll
  for (int off = 1; off < 16; off <<= 1) {
    tAs += __shfl_xor(tAs, off);
    tAd += __shfl_xor(tAd, off);
    tBs += __shfl_xor(tBs, off);
    tBd += __shfl_xor(tBd, off);
  }
  const float adA = tAd, adB = tBd;
  float eA = tAs + adA, eB = tBs + adB;
  eA = (eA > 0.f) ? eA : kNegSlope * eA;
  eB = (eB > 0.f) ? eB : kNegSlope * eB;
  const float wsA = fexp(eA);
  const float wsB = fexp(eB);
  float dA = wsA, dB = wsB;
  float aA[8], aB[8];
#pragma unroll
  for (int j = 0; j < 8; ++j) {
    aA[j] = wsA * fsA[j];
    aB[j] = wsB * fsB[j];
  }
  const int cm = (c0 > c1) ? c0 : c1;
  int i = 1;
  for (; i + 2 <= cm; i += 2) {
    const int jA0 = (i < c0) ? i : 0, jA1 = (i + 1 < c0) ? i + 1 : 0;
    const int jB0 = (i < c1) ? i : 0, jB1 = (i + 1 < c1) ? i + 1 : 0;
    const int sA0 = csr_src[s0 + jA0];
    const int sA1 = csr_src[s0 + jA1];
    const int sB0 = csr_src[s1 + jB0];
    const int sB1 = csr_src[s1 + jB1];
    const half8 vA0 = *(const half8*)(h + (size_t)sA0 * 512 + ch);
    const half8 vA1 = *(const half8*)(h + (size_t)sA1 * 512 + ch);
    const half8 vB0 = *(const half8*)(h + (size_t)sB0 * 512 + ch);
    const half8 vB1 = *(const half8*)(h + (size_t)sB1 * 512 + ch);
    float fA0[8], fA1[8], fB0[8], fB1[8];
    float tA0 = 0.f, tA1 = 0.f, tB0 = 0.f, tB1 = 0.f;
#pragma unroll
    for (int j = 0; j < 8; ++j) {
      fA0[j] = (float)vA0[j]; tA0 = fmaf(fA0[j], as_r[j], tA0);
      fA1[j] = (float)vA1[j]; tA1 = fmaf(fA1[j], as_r[j], tA1);
      fB0[j] = (float)vB0[j]; tB0 = fmaf(fB0[j], as_r[j], tB0);
      fB1[j] = (float)vB1[j]; tB1 = fmaf(fB1[j], as_r[j], tB1);
    }
#pragma unroll
    for (int off = 1; off < 16; off <<= 1) {
      tA0 += __shfl_xor(tA0, off);
      tA1 += __shfl_xor(tA1, off);
      tB0 += __shfl_xor(tB0, off);
      tB1 += __shfl_xor(tB1, off);
    }
    float eA0 = tA0 + adA, eA1 = tA1 + adA;
    float eB0 = tB0 + adB, eB1 = tB1 + adB;
    eA0 = (eA0 > 0.f) ? eA0 : kNegSlope * eA0;
    eA1 = (eA1 > 0.f) ? eA1 : kNegSlope * eA1;
    eB0 = (eB0 > 0.f) ? eB0 : kNegSlope * eB0;
    eB1 = (eB1 > 0.f) ? eB1 : kNegSlope * eB1;
    const float wA0 = (i < c0) ? fexp(eA0) : 0.f;
    const float wA1 = (i + 1 < c0) ? fexp(eA1) : 0.f;
    const float wB0 = (i < c1) ? fexp(eB0) : 0.f;
    const float wB1 = (i + 1 < c1) ? fexp(eB1) : 0.f;
    dA += wA0 + wA1;
    dB += wB0 + wB1;
#pragma unroll
    for (int j = 0; j < 8; ++j) {
      aA[j] = fmaf(wA0, fA0[j], aA[j]);
      aA[j] = fmaf(wA1, fA1[j], aA[j]);
      aB[j] = fmaf(wB0, fB0[j], aB[j]);
      aB[j] = fmaf(wB1, fB1[j], aB[j]);
    }
  }
  if (i < cm) {  // tail: at most one edge per node
    const int jA = (i < c0) ? i : 0;
    const int jB = (i < c1) ? i : 0;
    const int sA = csr_src[s0 + jA];
    const int sB = csr_src[s1 + jB];
    const half8 vA = *(const half8*)(h + (size_t)sA * 512 + ch);
    const half8 vB = *(const half8*)(h + (size_t)sB * 512 + ch);
    float fA[8], fB[8];
    float tA = 0.f, tB = 0.f;
#pragma unroll
    for (int j = 0; j < 8; ++j) {
      fA[j] = (float)vA[j]; tA = fmaf(fA[j], as_r[j], tA);
      fB[j] = (float)vB[j]; tB = fmaf(fB[j], as_r[j], tB);
    }
#pragma unroll
    for (int off = 1; off < 16; off <<= 1) {
      tA += __shfl_xor(tA, off);
      tB += __shfl_xor(tB, off);
    }
    float eA2 = tA + adA, eB2 = tB + adB;
    eA2 = (eA2 > 0.f) ? eA2 : kNegSlope * eA2;
    eB2 = (eB2 > 0.f) ? eB2 : kNegSlope * eB2;
    const float wA = (i < c0) ? fexp(eA2) : 0.f;
    const float wB = (i < c1) ? fexp(eB2) : 0.f;
    dA += wA;
    dB += wB;
#pragma unroll
    for (int j = 0; j < 8; ++j) {
      aA[j] = fmaf(wA, fA[j], aA[j]);
      aB[j] = fmaf(wB, fB[j], aB[j]);
    }
  }
  const float invA = 1.f / (dA + 1e-16f);
  const float invB = 1.f / (dB + 1e-16f);
  half8 HA, HB;
#pragma unroll
  for (int j = 0; j < 8; ++j) {
    float vA = aA[j] * invA + bias[ch + j];
    vA = (vA > 0.f) ? vA : (fexp(vA) - 1.f);  // elu via hw exp
    HA[j] = (_Float16)vA;
    float vB = aB[j] * invB + bias[ch + j];
    vB = (vB > 0.f) ? vB : (fexp(vB) - 1.f);
    HB[j] = (_Float16)vB;
  }
  *(half8*)(outH + (size_t)n0 * 512 + ch) = HA;
  if (has1) *(half8*)(outH + (size_t)n1r * 512 + ch) = HB;
}

// ---------- GAT aggregate, layer 3 (H=1, f16 h, 2 nodes/wave) ---------
__global__ void gat_agg_l3(const _Float16* __restrict__ h,
                           const float* __restrict__ a_src,
                           const float* __restrict__ a_dst,
                           const int* __restrict__ start, const int* __restrict__ cnt,
                           const int* __restrict__ csr_src,
                           const float* __restrict__ bias,
                           float* __restrict__ out, int n_nodes) {
  const int gtid = blockIdx.x * blockDim.x + threadIdx.x;
  const int wid = gtid >> 6;
  const int lane = threadIdx.x & 63;
  const int n0 = wid * 2;
  if (n0 >= n_nodes) return;
  const int n1r = (n0 + 1 < n_nodes) ? (n0 + 1) : n0;
  const bool has1 = (n0 + 1 < n_nodes);
  const float2 asv = *(const float2*)(a_src + lane * 2);
  const float2 adv = *(const float2*)(a_dst + lane * 2);
  const int s0 = start[n0], c0 = cnt[n0];
  const int s1 = start[n1r];
  const int c1 = has1 ? cnt[n1r] : 0;
  // self gathers
  const half2v vsA = *(const half2v*)(h + (size_t)n0 * 128 + lane * 2);
  const half2v vsB = *(const half2v*)(h + (size_t)n1r * 128 + lane * 2);
  const float xA = (float)vsA[0], yA = (float)vsA[1];
  const float xB = (float)vsB[0], yB = (float)vsB[1];
  float tAs = fmaf(xA, asv.x, yA * asv.y);
  float tAd = fmaf(xA, adv.x, yA * adv.y);
  float tBs = fmaf(xB, asv.x, yB * asv.y);
  float tBd = fmaf(xB, adv.x, yB * adv.y);
#pragma unroll
  for (int off = 1; off < 64; off <<= 1) {
    tAs += __shfl_xor(tAs, off);
    tAd += __shfl_xor(tAd, off);
    tBs += __shfl_xor(tBs, off);
    tBd += __shfl_xor(tBd, off);
  }
  const float adA = tAd, adB = tBd;
  float eA = tAs + adA, eB = tBs + adB;
  eA = (eA > 0.f) ? eA : kNegSlope * eA;
  eB = (eB > 0.f) ? eB : kNegSlope * eB;
  const float wsA = fexp(eA);
  const float wsB = fexp(eB);
  float dA = wsA, dB = wsB;
  float2 aA = make_float2(wsA * xA, wsA * yA);
  float2 aB = make_float2(wsB * xB, wsB * yB);
  const int cm = (c0 > c1) ? c0 : c1;
  int i = 1;
  for (; i + 2 <= cm; i += 2) {
    const int jA0 = (i < c0) ? i : 0, jA1 = (i + 1 < c0) ? i + 1 : 0;
    const int jB0 = (i < c1) ? i : 0, jB1 = (i + 1 < c1) ? i + 1 : 0;
    const int sA0 = csr_src[s0 + jA0];
    const int sA1 = csr_src[s0 + jA1];
    const int sB0 = csr_src[s1 + jB0];
    const int sB1 = csr_src[s1 + jB1];
    const half2v vA0 = *(const half2v*)(h + (size_t)sA0 * 128 + lane * 2);
    const half2v vA1 = *(const half2v*)(h + (size_t)sA1 * 128 + lane * 2);
    const half2v vB0 = *(const half2v*)(h + (size_t)sB0 * 128 + lane * 2);
    const half2v vB1 = *(const half2v*)(h + (size_t)sB1 * 128 + lane * 2);
    const float xA0 = (float)vA0[0], yA0 = (float)vA0[1];
    const float xA1 = (float)vA1[0], yA1 = (float)vA1[1];
    const float xB0 = (float)vB0[0], yB0 = (float)vB0[1];
    const float xB1 = (float)vB1[0], yB1 = (float)vB1[1];
    float tA0 = fmaf(xA0, asv.x, yA0 * asv.y);
    float tA1 = fmaf(xA1, asv.x, yA1 * asv.y);
    float tB0 = fmaf(xB0, asv.x, yB0 * asv.y);
    float tB1 = fmaf(xB1, asv.x, yB1 * asv.y);
#pragma unroll
    for (int off = 1; off < 64; off <<= 1) {
      tA0 += __shfl_xor(tA0, off);
      tA1 += __shfl_xor(tA1, off);
      tB0 += __shfl_xor(tB0, off);
      tB1 += __shfl_xor(tB1, off);
    }
    float eA0 = tA0 + adA, eA1 = tA1 + adA;
    float eB0 = tB0 + adB, eB1 = tB1 + adB;
    eA0 = (eA0 > 0.f) ? eA0 : kNegSlope * eA0;
    eA1 = (eA1 > 0.f) ? eA1 : kNegSlope * eA1;
    eB0 = (eB0 > 0.f) ? eB0 : kNegSlope * eB0;
    eB1 = (eB1 > 0.f) ? eB1 : kNegSlope * eB1;
    const float wA0 = (i < c0) ? fexp(eA0) : 0.f;
    const float wA1 = (i + 1 < c0) ? fexp(eA1) : 0.f;
    const float wB0 = (i < c1) ? fexp(eB0) : 0.f;
    const float wB1 = (i + 1 < c1) ? fexp(eB1) : 0.f;
    dA += wA0 + wA1;
    dB += wB0 + wB1;
    aA.x = fmaf(wA0, xA0, aA.x); aA.x = fmaf(wA1, xA1, aA.x);
    aA.y = fmaf(wA0, yA0, aA.y); aA.y = fmaf(wA1, yA1, aA.y);
    aB.x = fmaf(wB0, xB0, aB.x); aB.x = fmaf(wB1, xB1, aB.x);
    aB.y = fmaf(wB0, yB0, aB.y); aB.y = fmaf(wB1, yB1, aB.y);
  }
  if (i < cm) {
    const int jA = (i < c0) ? i : 0;
    const int jB = (i < c1) ? i : 0;
    const int sA = csr_src[s0 + jA];
    const int sB = csr_src[s1 + jB];
    const half2v vA = *(const half2v*)(h + (size_t)sA * 128 + lane * 2);
    const half2v vB = *(const half2v*)(h + (size_t)sB * 128 + lane * 2);
    const float xA2 = (float)vA[0], yA2 = (float)vA[1];
    const float xB2 = (float)vB[0], yB2 = (float)vB[1];
    float tA = fmaf(xA2, asv.x, yA2 * asv.y);
    float tB = fmaf(xB2, asv.x, yB2 * asv.y);
#pragma unroll
    for (int off = 1; off < 64; off <<= 1) {
      tA += __shfl_xor(tA, off);
      tB += __shfl_xor(tB, off);
    }
    float eA2 = tA + adA, eB2 = tB + adB;
    eA2 = (eA2 > 0.f) ? eA2 : kNegSlope * eA2;
    eB2 = (eB2 > 0.f) ? eB2 : kNegSlope * eB2;
    const float wA = (i < c0) ? fexp(eA2) : 0.f;
    const float wB = (i < c1) ? fexp(eB2) : 0.f;
    dA += wA;
    dB += wB;
    aA.x = fmaf(wA, xA2, aA.x);
    aA.y = fmaf(wA, yA2, aA.y);
    aB.x = fmaf(wB, xB2, aB.x);
    aB.y = fmaf(wB, yB2, aB.y);
  }
  const float invA = 1.f / (dA + 1e-16f);
  const float invB = 1.f / (dB + 1e-16f);
  *(float2*)(out + (size_t)n0 * 128 + lane * 2) =
      make_float2(aA.x * invA + bias[lane * 2],
                  aA.y * invA + bias[lane * 2 + 1]);
  if (has1)
    *(float2*)(out + (size_t)n1r * 128 + lane * 2) =
        make_float2(aB.x * invB + bias[lane * 2],
                    aB.y * invB + bias[lane * 2 + 1]);
}

// ------- global max pool over sorted batch (both encoders, 1 launch) ---
__global__ void pool_max2(const float* __restrict__ x, const int* __restrict__ bt1,
                          const int* __restrict__ bt2, float* __restrict__ emb) {
  __shared__ int lohi[2];
  const int enc = blockIdx.x >> 8;
  const int g = blockIdx.x & 255;
  const int* batch = enc ? bt2 : bt1;
  const float* xx = x + (size_t)enc * kN * 128;
  if (threadIdx.x == 0) {
    int lo = 0, hi = kN;
    while (lo < hi) {
      const int mid = (lo + hi) >> 1;
      if (batch[mid] < g) lo = mid + 1; else hi = mid;
    }
    lohi[0] = lo;
    hi = kN;
    while (lo < hi) {
      const int mid = (lo + hi) >> 1;
      if (batch[mid] < g + 1) lo = mid + 1; else hi = mid;
    }
    lohi[1] = lo;
  }
  __syncthreads();
  const int lo = lohi[0], hi = lohi[1];
  const int c = threadIdx.x;  // 128 channels
  float m = -1e30f;
  for (int nid = lo; nid < hi; ++nid) m = fmaxf(m, xx[(size_t)nid * 128 + c]);
  emb[(size_t)blockIdx.x * 128 + c] = (lo < hi) ? m : 0.f;
}
// ------- single-encoder pool (fallback path) --------------------------
__global__ void pool_max(const float* __restrict__ x, const int* __restrict__ batch,
                         float* __restrict__ emb, int n_nodes) {
  __shared__ int lohi[2];
  const int g = blockIdx.x;
  if (threadIdx.x == 0) {
    int lo = 0, hi = n_nodes;
    while (lo < hi) {
      const int mid = (lo + hi) >> 1;
      if (batch[mid] < g) lo = mid + 1; else hi = mid;
    }
    lohi[0] = lo;
    hi = n_nodes;
    while (lo < hi) {
      const int mid = (lo + hi) >> 1;
      if (batch[mid] < g + 1) lo = mid + 1; else hi = mid;
    }
    lohi[1] = lo;
  }
  __syncthreads();
  const int lo = lohi[0], hi = lohi[1];
  const int c = threadIdx.x;  // 128 channels
  float m = -1e30f;
  for (int nid = lo; nid < hi; ++nid) m = fmaxf(m, x[(size_t)nid * 128 + c]);
  emb[g * 128 + c] = (lo < hi) ? m : 0.f;
}

// ---------------- final MLP head --------------------------------------
__global__ void mlp_head(const float* __restrict__ e1, const float* __restrict__ e2,
                         const float* __restrict__ mw1, const float* __restrict__ mb1,
                         const float* __restrict__ mw2, const float* __restrict__ mb2,
                         float* __restrict__ out) {
  __shared__ float z[256];
  __shared__ float red[128];
  const int g = blockIdx.x;
  const int j = threadIdx.x;  // 128
  z[j] = e1[g * 128 + j];
  z[j + 128] = e2[g * 128 + j];
  __syncthreads();
  float acc = mb1[j];
  for (int k = 0; k < 256; ++k) acc = fmaf(z[k], mw1[k * 128 + j], acc);
  acc = fmaxf(acc, 0.f) * mw2[j];
  red[j] = acc;
  __syncthreads();
  for (int s = 64; s > 0; s >>= 1) {
    if (j < s) red[j] += red[j + s];
    __syncthreads();
  }
  if (j == 0) out[g] = red[0] + mb2[0];
}

// ---------------- launcher --------------------------------------------
namespace {
struct Bufs {
  _Float16 *R1h, *R2h;
  float *R1f, *R2f, *asrc, *adst;
  int *cnt, *start, *cursor, *csr, *total;
  _Float16 *Wth1, *Wth2, *Wth3;
  float* emb;
  size_t need;
};

Bufs plan(void* d_ws, int M, int E) {
  Bufs b;
  char* w = (char*)d_ws;
  size_t off = 0;
  auto take = [&](size_t bytes) -> void* {
    void* p = w + off;
    off += (bytes + 255) & ~(size_t)255;
    return p;
  };
  b.R1h = (_Float16*)take((size_t)M * 512 * 2);  // f16 activations
  b.R1f = (float*)b.R1h;                         // layer-3 out alias [M,128]
  b.R2h = (_Float16*)take((size_t)M * 512 * 2);  // h f16 (l3 h f16 [M,128])
  b.R2f = (float*)b.R2h;
  b.asrc = (float*)take((size_t)M * 4 * 4);      // (kept for ws layout stability)
  b.adst = (float*)take((size_t)M * 4 * 4);
  b.cnt = (int*)take((size_t)M * 4);
  b.start = (int*)take((size_t)M * 4);
  b.cursor = (int*)take((size_t)M * 4);
  b.csr = (int*)take((size_t)E * 4);
  b.total = (int*)take(256);
  b.Wth1 = (_Float16*)take((size_t)64 * 512 * 2);
  b.Wth2 = (_Float16*)take((size_t)512 * 512 * 2);
  b.Wth3 = (_Float16*)take((size_t)512 * 128 * 2);
  b.emb = (float*)take((size_t)2 * kG * 128 * 4);
  b.need = off;
  return b;
}

void run_layers(const Bufs& b, void* const* d_in, int M, hipStream_t stream) {
  const float* as1 = (const float*)d_in[7];
  const float* ad1 = (const float*)d_in[8];
  const float* b1 = (const float*)d_in[9];
  const float* as2 = (const float*)d_in[11];
  const float* ad2 = (const float*)d_in[12];
  const float* b2 = (const float*)d_in[13];
  const float* as3 = (const float*)d_in[15];
  const float* ad3 = (const float*)d_in[16];
  const float* b3 = (const float*)d_in[17];
  const int aggBlocks = (((M + 1) / 2) * 64 + 255) / 256;  // 2 nodes/wave
  const int MT = (M + 255) / 256;         // 256-row tiles
  const int SP = (MT + 7) / 8;            // row-tile groups of 8 (XCD map)

  // layer 1: [M,64] @ [64,512], h -> f16 (A1h aliases R1h)
  gemm_ring<1, 256, 2><<<SP * 16, 512, 0, stream>>>(b.R1h, b.Wth1, b.R2h, M, 512, 64);
  gat_agg4<<<aggBlocks, 256, 0, stream>>>(b.R2h, as1, ad1, b.start, b.cnt,
                                          b.csr, b1, b.R1h, M);
  // layer 2: [M,512] @ [512,512], h -> f16
  gemm_ring<1, 256, 2><<<SP * 16, 512, 0, stream>>>(b.R1h, b.Wth2, b.R2h, M, 512, 512);
  gat_agg4<<<aggBlocks, 256, 0, stream>>>(b.R2h, as2, ad2, b.start, b.cnt,
                                          b.csr, b2, b.R1h, M);
  // layer 3: [M,512] @ [512,128], H=1, no elu, h -> f16
  gemm_ring<1, 128, 1><<<SP * 8, 512, 0, stream>>>(b.R1h, b.Wth3, b.R2h, M, 128, 512);
  gat_agg_l3<<<aggBlocks, 256, 0, stream>>>(b.R2h, as3, ad3, b.start, b.cnt,
                                            b.csr, b3, b.R1f, M);
}
}  // namespace

extern "C" void kernel_launch(void* const* d_in, const int* in_sizes, int n_in,
                              void* d_out, int out_size, void* d_ws, size_t ws_size,
                              hipStream_t stream) {
  (void)in_sizes; (void)n_in; (void)out_size;
  const float* W1 = (const float*)d_in[6];
  const float* W2 = (const float*)d_in[10];
  const float* W3 = (const float*)d_in[14];
  const float* mw1 = (const float*)d_in[18];
  const float* mb1 = (const float*)d_in[19];
  const float* mw2 = (const float*)d_in[20];
  const float* mb2 = (const float*)d_in[21];

  // Prefer combined (both encoders batched, M=2N) if it fits the workspace.
  Bufs bc = plan(d_ws, 2 * kN, 2 * kE2);
  const bool combined = bc.need <= ws_size;
  Bufs b = combined ? bc : plan(d_ws, kN, kE2);

  const int wtot = 64 * 512 + 512 * 512 + 512 * 128;
  if (combined) {
    const int M = 2 * kN;
    const int* ei0 = (const int*)d_in[1];
    const int* ei1 = (const int*)d_in[4];
    prep_all<<<(M * 64 + wtot + 255) / 256, 256, 0, stream>>>(
        (const float*)d_in[0], (const float*)d_in[3], b.R1h, b.cnt, b.total,
        W1, b.Wth1, W2, b.Wth2, W3, b.Wth3);
    count_edges2<<<(2 * kE + 255) / 256, 256, 0, stream>>>(ei0 + kE, ei1 + kE,
                                                           b.cnt);
    alloc_ranges<<<(M + 255) / 256, 256, 0, stream>>>(b.cnt, b.start, b.cursor,
                                                      b.total, b.csr, M);
    fill_edges2<<<(2 * kE + 255) / 256, 256, 0, stream>>>(ei0, ei0 + kE, ei1,
                                                          ei1 + kE, b.cursor, b.csr);
    run_layers(b, d_in, M, stream);
    pool_max2<<<2 * kG, 128, 0, stream>>>(b.R1f, (const int*)d_in[2],
                                          (const int*)d_in[5], b.emb);
  } else {
    wt_split_all<<<(wtot + 255) / 256, 256, 0, stream>>>(W1, b.Wth1, W2, b.Wth2,
                                                         W3, b.Wth3);
    for (int enc = 0; enc < 2; ++enc) {
      const float* x = (const float*)d_in[enc * 3 + 0];
      const int* ei = (const int*)d_in[enc * 3 + 1];
      const int* batch = (const int*)d_in[enc * 3 + 2];
      prep<<<(kN * 64 + 255) / 256, 256, 0, stream>>>(x, b.R1h, b.cnt, b.total,
                                                      kN * 64, kN);
      count_edges<<<(kE + 255) / 256, 256, 0, stream>>>(ei + kE, b.cnt, kE);
      alloc_ranges<<<(kN + 255) / 256, 256, 0, stream>>>(b.cnt, b.start, b.cursor,
                                                         b.total, b.csr, kN);
      fill_edges<<<(kE + 255) / 256, 256, 0, stream>>>(ei, ei + kE, b.cursor, b.csr,
                                                       kE);
      run_layers(b, d_in, kN, stream);
      pool_max<<<kG, 128, 0, stream>>>(b.R1f, batch, b.emb + (size_t)enc * kG * 128,
                                       kN);
    }
  }
  mlp_head<<<kG, 128, 0, stream>>>(b.emb, b.emb + (size_t)kG * 128, mw1, mb1, mw2,
                                   mb2, (float*)d_out);
}

// Round 9
// 633.217 us; speedup vs baseline: 1.3382x; 1.0034x over previous
//
#include <hip/hip_runtime.h>
#include <cstdint>

namespace {
constexpr int kN = 50000;          // nodes per encoder
constexpr int kE = 200000;         // directed edges per encoder (pre self-loop)
constexpr int kE2 = kE + kN;       // with self loops (per encoder)
constexpr int kG = 256;            // graphs per encoder
constexpr float kNegSlope = 0.2f;
}

using half8   = __attribute__((ext_vector_type(8))) _Float16;
using half2v  = __attribute__((ext_vector_type(2))) _Float16;
using floatx4 = __attribute__((ext_vector_type(4))) float;

__device__ __forceinline__ void gld_lds16(const void* g, void* l) {
  __builtin_amdgcn_global_load_lds(
      (const __attribute__((address_space(1))) unsigned int*)g,
      (__attribute__((address_space(3))) unsigned int*)l, 16, 0, 0);
}

// fast exp: e^x = 2^(x*log2(e)) via hardware v_exp_f32 (no libm call)
__device__ __forceinline__ float fexp(float x) {
  return __builtin_amdgcn_exp2f(x * 1.44269504088896f);
}

// ---------------- fp16 MFMA GEMM: C[M,N] = A[M,K] @ B[K,N] -----------
// R21: 128xBN tile, 4 waves, 3-slot ring (24KB/16KB slots, 72/48KB LDS)
// -> 2-3 blocks/CU. R20 (single-barrier ring, 256^2, 1 block/CU) proved
// barrier count is NOT the cost; at 1 block/CU there is no inter-block
// overlap and the 784-block grid quantizes to 4 makespan rounds for
// 3.06 rounds of work. Halving the block footprint restores the m97/
// m114 mechanism: two independent resident blocks cover each other's
// stalls, and the tail is finer-grained. Schedule per tile is unchanged:
// counted vmcnt(LPT) (never 0 in loop), ONE barrier, stage kt+2 into
// slot (kt-1)%3 (freed by the barrier: every wave's MFMAs for tile kt-1
// issued before it arrives, and MFMA issue forces ds_read completion).
template <int OUTF16, int BN, int CT>
__global__ __launch_bounds__(256, 2) void gemm_ring(
    const _Float16* __restrict__ A, const _Float16* __restrict__ B,
    void* __restrict__ Cv, int M, int N, int K) {
  constexpr int ASL = 512;                 // A slots/tile (128 rows x 32k x 2B /16)
  constexpr int BSL = BN * 4;              // B slots/tile (1024 or 512)
  constexpr int SLOT = (ASL + BSL) * 16;   // 24KB or 16KB
  constexpr int LPT = (ASL + BSL) / 256;   // loads/thread/tile: 6 or 4
  constexpr int WTM = 64;                  // 2 waves along M
  constexpr int WTN = BN / 2;              // 2 waves along N (128 or 64)
  constexpr int MI = WTM / 16;             // 4
  constexpr int NI = WTN / 16;             // 8 or 4
  __shared__ alignas(16) char smem[3 * SLOT];  // 72KB or 48KB ring
  const int t = threadIdx.x;
  const int w = t >> 6, l = t & 63;
  const int x = blockIdx.x & 7, s = blockIdx.x >> 3;
  const int col = (CT == 1) ? 0 : (s & (CT - 1));
  const int rt = ((CT == 1) ? s : (s >> 1)) * 8 + x;
  const int bm = rt * 128;
  const int bn = col * BN;
  if (bm >= M) return;  // padded row-tiles: whole block exits (no barrier)
  const int wr = w >> 1, wc = w & 1;
  const int quad = l >> 4, lrow = l & 15;

  floatx4 acc[MI][NI];
#pragma unroll
  for (int mi = 0; mi < MI; ++mi)
#pragma unroll
    for (int ni = 0; ni < NI; ++ni) acc[mi][ni] = (floatx4){0.f, 0.f, 0.f, 0.f};

  // stage tile kt's A-part / B-part into the given ring slot
  auto stageA = [&](int slot, int kt) {
    char* buf = smem + (size_t)slot * SLOT;
    int k0 = kt * 32;
    k0 = (k0 > K - 32) ? (K - 32) : k0;  // clamp: beyond-NT garbage stays in-bounds
#pragma unroll
    for (int i = 0; i < ASL / 256; ++i) {  // 2
      const int sl = i * 256 + t;
      const int row = ((sl >> 6) << 4) + (sl & 15);
      const int q = (sl >> 4) & 3;
      int ga = bm + row;
      ga = (ga < M) ? ga : (M - 1);      // clamp: keep lanes active
      gld_lds16(A + (size_t)ga * K + k0 + q * 8, buf + sl * 16);
    }
  };
  auto stageB = [&](int slot, int kt) {
    char* buf = smem + (size_t)slot * SLOT + ASL * 16;
    int k0 = kt * 32;
    k0 = (k0 > K - 32) ? (K - 32) : k0;
#pragma unroll
    for (int i = 0; i < BSL / 256; ++i) {  // 4 or 2
      const int sl = i * 256 + t;
      const int row = ((sl >> 6) << 4) + (sl & 15);
      const int q = (sl >> 4) & 3;
      gld_lds16(B + (size_t)(bn + row) * K + k0 + q * 8, buf + sl * 16);
    }
  };

  // prologue: tiles 0,1 in flight (2*LPT loads), distance-2 ring
  stageA(0, 0); stageB(0, 0);
  stageA(1, 1); stageB(1, 1);

  const int NT = K >> 5;
  int cur = 0;
  for (int kt = 0; kt < NT; ++kt) {
    char* bufc = smem + (size_t)cur * SLOT;
    const int stg = (cur == 0) ? 2 : (cur - 1);  // (cur+2)%3
    // outstanding: tiles kt,kt+1 (2*LPT). Wait for tile kt's LPT.
    if constexpr (LPT == 6)
      asm volatile("s_waitcnt vmcnt(6)" ::: "memory");
    else
      asm volatile("s_waitcnt vmcnt(4)" ::: "memory");
    __builtin_amdgcn_s_barrier();  // slot[cur] ready AND slot[stg] consumed
    asm volatile("" ::: "memory");
    stageA(stg, kt + 2);           // -> slot of tile kt-1, safe after barrier
    half8 fa[MI], fb[NI];
#pragma unroll
    for (int ni = 0; ni < NI; ++ni)
      fb[ni] = *(const half8*)(bufc + ASL * 16 + ((wc * NI + ni) << 10) + l * 16);
#pragma unroll
    for (int mi = 0; mi < MI / 2; ++mi)
      fa[mi] = *(const half8*)(bufc + ((wr * MI + mi) << 10) + l * 16);
    __builtin_amdgcn_s_setprio(1);
#pragma unroll
    for (int mi = 0; mi < MI / 2; ++mi)
#pragma unroll
      for (int ni = 0; ni < NI; ++ni)
        acc[mi][ni] = __builtin_amdgcn_mfma_f32_16x16x32_f16(
            fa[mi], fb[ni], acc[mi][ni], 0, 0, 0);
    __builtin_amdgcn_s_setprio(0);
    stageB(stg, kt + 2);           // remaining loads of tile kt+2
#pragma unroll
    for (int mi = MI / 2; mi < MI; ++mi)
      fa[mi] = *(const half8*)(bufc + ((wr * MI + mi) << 10) + l * 16);
    __builtin_amdgcn_s_setprio(1);
#pragma unroll
    for (int mi = MI / 2; mi < MI; ++mi)
#pragma unroll
      for (int ni = 0; ni < NI; ++ni)
        acc[mi][ni] = __builtin_amdgcn_mfma_f32_16x16x32_f16(
            fa[mi], fb[ni], acc[mi][ni], 0, 0, 0);
    __builtin_amdgcn_s_setprio(0);
    cur = (cur == 2) ? 0 : (cur + 1);
    // no end-of-tile barrier: distance-2 ring tolerates the drift
  }
  asm volatile("s_waitcnt vmcnt(0)" ::: "memory");  // drain garbage prefetches
  // epilogue: C/D layout col=lane&15, row=quad*4+reg
  const int colbase = bn + wc * WTN + lrow;
#pragma unroll
  for (int mi = 0; mi < MI; ++mi) {
    const int rbase = bm + wr * WTM + mi * 16 + quad * 4;
#pragma unroll
    for (int r = 0; r < 4; ++r) {
      const int grow = rbase + r;
      if (grow < M) {
        if constexpr (OUTF16) {
          _Float16* C = (_Float16*)Cv;
#pragma unroll
          for (int ni = 0; ni < NI; ++ni)
            C[(size_t)grow * N + colbase + ni * 16] = (_Float16)acc[mi][ni][r];
        } else {
          float* C = (float*)Cv;
#pragma unroll
          for (int ni = 0; ni < NI; ++ni)
            C[(size_t)grow * N + colbase + ni * 16] = acc[mi][ni][r];
        }
      }
    }
  }
}

// ------- all three weight transposes + f16 casts (fallback path) ------
__global__ void wt_split_all(const float* __restrict__ W1, _Float16* Th1,
                             const float* __restrict__ W2, _Float16* Th2,
                             const float* __restrict__ W3, _Float16* Th3) {
  int idx = blockIdx.x * blockDim.x + threadIdx.x;
  const float* W;
  _Float16* Th;
  int K, N;
  if (idx < 64 * 512) {
    W = W1; Th = Th1; K = 64; N = 512;
  } else if (idx < 64 * 512 + 512 * 512) {
    idx -= 64 * 512;
    W = W2; Th = Th2; K = 512; N = 512;
  } else if (idx < 64 * 512 + 512 * 512 + 512 * 128) {
    idx -= 64 * 512 + 512 * 512;
    W = W3; Th = Th3; K = 512; N = 128;
  } else {
    return;
  }
  const int k = idx / N;
  const int n = idx - k * N;
  Th[n * K + k] = (_Float16)W[idx];
}

// --- combined prep: x casts + cnt=1 + total=0 + weight transposes -----
__global__ void prep_all(const float* __restrict__ x0, const float* __restrict__ x1,
                         _Float16* __restrict__ Xh, int* __restrict__ cnt,
                         int* __restrict__ total,
                         const float* __restrict__ W1, _Float16* Th1,
                         const float* __restrict__ W2, _Float16* Th2,
                         const float* __restrict__ W3, _Float16* Th3) {
  const int idx = blockIdx.x * blockDim.x + threadIdx.x;
  const int half = kN * 64;
  if (idx < half) {
    Xh[idx] = (_Float16)x0[idx];
  } else if (idx < 2 * half) {
    Xh[idx] = (_Float16)x1[idx - half];
  } else {
    int e = idx - 2 * half;
    const float* W;
    _Float16* Th;
    int K, N;
    if (e < 64 * 512) {
      W = W1; Th = Th1; K = 64; N = 512;
    } else if (e < 64 * 512 + 512 * 512) {
      e -= 64 * 512;
      W = W2; Th = Th2; K = 512; N = 512;
    } else if (e < 64 * 512 + 512 * 512 + 512 * 128) {
      e -= 64 * 512 + 512 * 512;
      W = W3; Th = Th3; K = 512; N = 128;
    } else {
      W = nullptr; Th = nullptr; K = N = 0;
    }
    if (W) {
      const int k = e / N;
      const int n = e - k * N;
      Th[n * K + k] = (_Float16)W[e];
    }
  }
  if (idx < 2 * kN) cnt[idx] = 1;  // the self loop
  if (idx == 0) *total = 0;
}
// ------- single-encoder prep (fallback path) --------------------------
__global__ void prep(const float* __restrict__ X, _Float16* __restrict__ Xh,
                     int* __restrict__ cnt, int* __restrict__ total, int nsplit,
                     int n) {
  const int idx = blockIdx.x * blockDim.x + threadIdx.x;
  if (idx < nsplit) Xh[idx] = (_Float16)X[idx];
  if (idx < n) cnt[idx] = 1;
  if (idx == 0) *total = 0;
}

// ---------------- CSR (by dst) build ----------------------------------
__global__ void count_edges2(const int* __restrict__ d0, const int* __restrict__ d1,
                             int* __restrict__ cnt) {
  const int i = blockIdx.x * blockDim.x + threadIdx.x;
  if (i < kE) atomicAdd(&cnt[d0[i]], 1);
  else if (i < 2 * kE) atomicAdd(&cnt[d1[i - kE] + kN], 1);
}
__global__ void fill_edges2(const int* __restrict__ s0, const int* __restrict__ d0,
                            const int* __restrict__ s1, const int* __restrict__ d1,
                            int* __restrict__ cursor, int* __restrict__ csr) {
  const int i = blockIdx.x * blockDim.x + threadIdx.x;
  if (i < kE) {
    const int p = atomicAdd(&cursor[d0[i]], 1);
    csr[p] = s0[i];
  } else if (i < 2 * kE) {
    const int j = i - kE;
    const int p = atomicAdd(&cursor[d1[j] + kN], 1);
    csr[p] = s1[j] + kN;
  }
}
__global__ void count_edges(const int* __restrict__ dst, int* __restrict__ cnt,
                            int ne) {
  const int i = blockIdx.x * blockDim.x + threadIdx.x;
  if (i < ne) atomicAdd(&cnt[dst[i]], 1);
}
__global__ void fill_edges(const int* __restrict__ src, const int* __restrict__ dst,
                           int* __restrict__ cursor, int* __restrict__ csr, int ne) {
  const int i = blockIdx.x * blockDim.x + threadIdx.x;
  if (i < ne) {
    const int p = atomicAdd(&cursor[dst[i]], 1);
    csr[p] = src[i];
  }
}
__global__ void alloc_ranges(const int* __restrict__ cnt, int* __restrict__ start,
                             int* __restrict__ cursor, int* __restrict__ total,
                             int* __restrict__ csr, int n) {
  const int i = blockIdx.x * blockDim.x + threadIdx.x;
  const int lane = threadIdx.x & 63;
  const int v = (i < n) ? cnt[i] : 0;
  int sc = v;
#pragma unroll
  for (int off = 1; off < 64; off <<= 1) {
    const int t = __shfl_up(sc, off);
    if (lane >= off) sc += t;
  }
  const int wtot = __shfl(sc, 63);
  int base = 0;
  if (lane == 63) base = atomicAdd(total, wtot);
  base = __shfl(base, 63);
  const int st = base + sc - v;
  if (i < n) {
    start[i] = st;
    cursor[i] = st + 1;
    csr[st] = i;  // self loop first
  }
}

// ---------------- GAT aggregate, layers 1-2 (f16 h) -------------------
// R19: TWO nodes per wave, interleaved — the serial chain is per-NODE
// (start/cnt -> csr idx -> gather, ~3 dependent misses); interleaving
// two nodes doubles every level of the chain in flight per wave.
__global__ void gat_agg4(const _Float16* __restrict__ h,
                         const float* __restrict__ a_src,
                         const float* __restrict__ a_dst,
                         const int* __restrict__ start, const int* __restrict__ cnt,
                         const int* __restrict__ csr_src,
                         const float* __restrict__ bias,
                         _Float16* __restrict__ outH, int n_nodes) {
  const int gtid = blockIdx.x * blockDim.x + threadIdx.x;
  const int wid = gtid >> 6;
  const int lane = threadIdx.x & 63;
  const int n0 = wid * 2;
  if (n0 >= n_nodes) return;
  const int n1r = (n0 + 1 < n_nodes) ? (n0 + 1) : n0;
  const bool has1 = (n0 + 1 < n_nodes);
  const int ch = lane * 8;
  float as_r[8], ad_r[8];
#pragma unroll
  for (int j = 0; j < 8; ++j) {
    as_r[j] = a_src[ch + j];
    ad_r[j] = a_dst[ch + j];
  }
  const int s0 = start[n0], c0 = cnt[n0];
  const int s1 = start[n1r];
  const int c1 = has1 ? cnt[n1r] : 0;
  // self gathers for both nodes (csr[s]==node; gives dst-dot + self edge)
  const half8 vsA = *(const half8*)(h + (size_t)n0 * 512 + ch);
  const half8 vsB = *(const half8*)(h + (size_t)n1r * 512 + ch);
  float fsA[8], fsB[8];
  float tAs = 0.f, tAd = 0.f, tBs = 0.f, tBd = 0.f;
#pragma unroll
  for (int j = 0; j < 8; ++j) {
    fsA[j] = (float)vsA[j];
    fsB[j] = (float)vsB[j];
    tAs = fmaf(fsA[j], as_r[j], tAs);
    tAd = fmaf(fsA[j], ad_r[j], tAd);
    tBs = fmaf(fsB[j], as_r[j], tBs);
    tBd = fmaf(fsB[j], ad_r[j], tBd);
  }
#pragma unroll
  for (int off = 1; off < 16; off <<= 1) {
    tAs += __shfl_xor(tAs, off);
    tAd += __shfl_xor(tAd, off);
    tBs += __shfl_xor(tBs, off);
    tBd += __shfl_xor(tBd, off);
  }
  const float adA = tAd, adB = tBd;
  float eA = tAs + adA, eB = tBs + adB;
  eA = (eA > 0.f) ? eA : kNegSlope * eA;
  eB = (eB > 0.f) ? eB : kNegSlope * eB;
  const float wsA = fexp(eA);
  const float wsB = fexp(eB);
  float dA = wsA, dB = wsB;
  float aA[8], aB[8];
#pragma unroll
  for (int j = 0; j < 8; ++j) {
    aA[j] = wsA * fsA[j];
    aB[j] = wsB * fsB[j];
  }
  const int cm = (c0 > c1) ? c0 : c1;
  int i = 1;
  for (; i + 2 <= cm; i += 2) {
    const int jA0 = (i < c0) ? i : 0, jA1 = (i + 1 < c0) ? i + 1 : 0;
    const int jB0 = (i < c1) ? i : 0, jB1 = (i + 1 < c1) ? i + 1 : 0;
    const int sA0 = csr_src[s0 + jA0];
    const int sA1 = csr_src[s0 + jA1];
    const int sB0 = csr_src[s1 + jB0];
    const int sB1 = csr_src[s1 + jB1];
    const half8 vA0 = *(const half8*)(h + (size_t)sA0 * 512 + ch);
    const half8 vA1 = *(const half8*)(h + (size_t)sA1 * 512 + ch);
    const half8 vB0 = *(const half8*)(h + (size_t)sB0 * 512 + ch);
    const half8 vB1 = *(const half8*)(h + (size_t)sB1 * 512 + ch);
    float fA0[8], fA1[8], fB0[8], fB1[8];
    float tA0 = 0.f, tA1 = 0.f, tB0 = 0.f, tB1 = 0.f;
#pragma unroll
    for (int j = 0; j < 8; ++j) {
      fA0[j] = (float)vA0[j]; tA0 = fmaf(fA0[j], as_r[j], tA0);
      fA1[j] = (float)vA1[j]; tA1 = fmaf(fA1[j], as_r[j], tA1);
      fB0[j] = (float)vB0[j]; tB0 = fmaf(fB0[j], as_r[j], tB0);
      fB1[j] = (float)vB1[j]; tB1 = fmaf(fB1[j], as_r[j], tB1);
    }
#pragma unroll
    for (int off = 1; off < 16; off <<= 1) {
      tA0 += __shfl_xor(tA0, off);
      tA1 += __shfl_xor(tA1, off);
      tB0 += __shfl_xor(tB0, off);
      tB1 += __shfl_xor(tB1, off);
    }
    float eA0 = tA0 + adA, eA1 = tA1 + adA;
    float eB0 = tB0 + adB, eB1 = tB1 + adB;
    eA0 = (eA0 > 0.f) ? eA0 : kNegSlope * eA0;
    eA1 = (eA1 > 0.f) ? eA1 : kNegSlope * eA1;
    eB0 = (eB0 > 0.f) ? eB0 : kNegSlope * eB0;
    eB1 = (eB1 > 0.f) ? eB1 : kNegSlope * eB1;
    const float wA0 = (i < c0) ? fexp(eA0) : 0.f;
    const float wA1 = (i + 1 < c0) ? fexp(eA1) : 0.f;
    const float wB0 = (i < c1) ? fexp(eB0) : 0.f;
    const float wB1 = (i + 1 < c1) ? fexp(eB1) : 0.f;
    dA += wA0 + wA1;
    dB += wB0 + wB1;
#pragma unroll
    for (int j = 0; j < 8; ++j) {
      aA[j] = fmaf(wA0, fA0[j], aA[j]);
      aA[j] = fmaf(wA1, fA1[j], aA[j]);
      aB[j] = fmaf(wB0, fB0[j], aB[j]);
      aB[j] = fmaf(wB1, fB1[j], aB[j]);
    }
  }
  if (i < cm) {  // tail: at most one edge per node
    const int jA = (i < c0) ? i : 0;
    const int jB = (i < c1) ? i : 0;
    const int sA = csr_src[s0 + jA];
    const int sB = csr_src[s1 + jB];
    const half8 vA = *(const half8*)(h + (size_t)sA * 512 + ch);
    const half8 vB = *(const half8*)(h + (size_t)sB * 512 + ch);
    float fA[8], fB[8];
    float tA = 0.f, tB = 0.f;
#pragma unroll
    for (int j = 0; j < 8; ++j) {
      fA[j] = (float)vA[j]; tA = fmaf(fA[j], as_r[j], tA);
      fB[j] = (float)vB[j]; tB = fmaf(fB[j], as_r[j], tB);
    }
#pragma unroll
    for (int off = 1; off < 16; off <<= 1) {
      tA += __shfl_xor(tA, off);
      tB += __shfl_xor(tB, off);
    }
    float eA2 = tA + adA, eB2 = tB + adB;
    eA2 = (eA2 > 0.f) ? eA2 : kNegSlope * eA2;
    eB2 = (eB2 > 0.f) ? eB2 : kNegSlope * eB2;
    const float wA = (i < c0) ? fexp(eA2) : 0.f;
    const float wB = (i < c1) ? fexp(eB2) : 0.f;
    dA += wA;
    dB += wB;
#pragma unroll
    for (int j = 0; j < 8; ++j) {
      aA[j] = fmaf(wA, fA[j], aA[j]);
      aB[j] = fmaf(wB, fB[j], aB[j]);
    }
  }
  const float invA = 1.f / (dA + 1e-16f);
  const float invB = 1.f / (dB + 1e-16f);
  half8 HA, HB;
#pragma unroll
  for (int j = 0; j < 8; ++j) {
    float vA = aA[j] * invA + bias[ch + j];
    vA = (vA > 0.f) ? vA : (fexp(vA) - 1.f);  // elu via hw exp
    HA[j] = (_Float16)vA;
    float vB = aB[j] * invB + bias[ch + j];
    vB = (vB > 0.f) ? vB : (fexp(vB) - 1.f);
    HB[j] = (_Float16)vB;
  }
  *(half8*)(outH + (size_t)n0 * 512 + ch) = HA;
  if (has1) *(half8*)(outH + (size_t)n1r * 512 + ch) = HB;
}

// ---------- GAT aggregate, layer 3 (H=1, f16 h, 2 nodes/wave) ---------
__global__ void gat_agg_l3(const _Float16* __restrict__ h,
                           const float* __restrict__ a_src,
                           const float* __restrict__ a_dst,
                           const int* __restrict__ start, const int* __restrict__ cnt,
                           const int* __restrict__ csr_src,
                           const float* __restrict__ bias,
                           float* __restrict__ out, int n_nodes) {
  const int gtid = blockIdx.x * blockDim.x + threadIdx.x;
  const int wid = gtid >> 6;
  const int lane = threadIdx.x & 63;
  const int n0 = wid * 2;
  if (n0 >= n_nodes) return;
  const int n1r = (n0 + 1 < n_nodes) ? (n0 + 1) : n0;
  const bool has1 = (n0 + 1 < n_nodes);
  const float2 asv = *(const float2*)(a_src + lane * 2);
  const float2 adv = *(const float2*)(a_dst + lane * 2);
  const int s0 = start[n0], c0 = cnt[n0];
  const int s1 = start[n1r];
  const int c1 = has1 ? cnt[n1r] : 0;
  // self gathers
  const half2v vsA = *(const half2v*)(h + (size_t)n0 * 128 + lane * 2);
  const half2v vsB = *(const half2v*)(h + (size_t)n1r * 128 + lane * 2);
  const float xA = (float)vsA[0], yA = (float)vsA[1];
  const float xB = (float)vsB[0], yB = (float)vsB[1];
  float tAs = fmaf(xA, asv.x, yA * asv.y);
  float tAd = fmaf(xA, adv.x, yA * adv.y);
  float tBs = fmaf(xB, asv.x, yB * asv.y);
  float tBd = fmaf(xB, adv.x, yB * adv.y);
#pragma unroll
  for (int off = 1; off < 64; off <<= 1) {
    tAs += __shfl_xor(tAs, off);
    tAd += __shfl_xor(tAd, off);
    tBs += __shfl_xor(tBs, off);
    tBd += __shfl_xor(tBd, off);
  }
  const float adA = tAd, adB = tBd;
  float eA = tAs + adA, eB = tBs + adB;
  eA = (eA > 0.f) ? eA : kNegSlope * eA;
  eB = (eB > 0.f) ? eB : kNegSlope * eB;
  const float wsA = fexp(eA);
  const float wsB = fexp(eB);
  float dA = wsA, dB = wsB;
  float2 aA = make_float2(wsA * xA, wsA * yA);
  float2 aB = make_float2(wsB * xB, wsB * yB);
  const int cm = (c0 > c1) ? c0 : c1;
  int i = 1;
  for (; i + 2 <= cm; i += 2) {
    const int jA0 = (i < c0) ? i : 0, jA1 = (i + 1 < c0) ? i + 1 : 0;
    const int jB0 = (i < c1) ? i : 0, jB1 = (i + 1 < c1) ? i + 1 : 0;
    const int sA0 = csr_src[s0 + jA0];
    const int sA1 = csr_src[s0 + jA1];
    const int sB0 = csr_src[s1 + jB0];
    const int sB1 = csr_src[s1 + jB1];
    const half2v vA0 = *(const half2v*)(h + (size_t)sA0 * 128 + lane * 2);
    const half2v vA1 = *(const half2v*)(h + (size_t)sA1 * 128 + lane * 2);
    const half2v vB0 = *(const half2v*)(h + (size_t)sB0 * 128 + lane * 2);
    const half2v vB1 = *(const half2v*)(h + (size_t)sB1 * 128 + lane * 2);
    const float xA0 = (float)vA0[0], yA0 = (float)vA0[1];
    const float xA1 = (float)vA1[0], yA1 = (float)vA1[1];
    const float xB0 = (float)vB0[0], yB0 = (float)vB0[1];
    const float xB1 = (float)vB1[0], yB1 = (float)vB1[1];
    float tA0 = fmaf(xA0, asv.x, yA0 * asv.y);
    float tA1 = fmaf(xA1, asv.x, yA1 * asv.y);
    float tB0 = fmaf(xB0, asv.x, yB0 * asv.y);
    float tB1 = fmaf(xB1, asv.x, yB1 * asv.y);
#pragma unroll
    for (int off = 1; off < 64; off <<= 1) {
      tA0 += __shfl_xor(tA0, off);
      tA1 += __shfl_xor(tA1, off);
      tB0 += __shfl_xor(tB0, off);
      tB1 += __shfl_xor(tB1, off);
    }
    float eA0 = tA0 + adA, eA1 = tA1 + adA;
    float eB0 = tB0 + adB, eB1 = tB1 + adB;
    eA0 = (eA0 > 0.f) ? eA0 : kNegSlope * eA0;
    eA1 = (eA1 > 0.f) ? eA1 : kNegSlope * eA1;
    eB0 = (eB0 > 0.f) ? eB0 : kNegSlope * eB0;
    eB1 = (eB1 > 0.f) ? eB1 : kNegSlope * eB1;
    const float wA0 = (i < c0) ? fexp(eA0) : 0.f;
    const float wA1 = (i + 1 < c0) ? fexp(eA1) : 0.f;
    const float wB0 = (i < c1) ? fexp(eB0) : 0.f;
    const float wB1 = (i + 1 < c1) ? fexp(eB1) : 0.f;
    dA += wA0 + wA1;
    dB += wB0 + wB1;
    aA.x = fmaf(wA0, xA0, aA.x); aA.x = fmaf(wA1, xA1, aA.x);
    aA.y = fmaf(wA0, yA0, aA.y); aA.y = fmaf(wA1, yA1, aA.y);
    aB.x = fmaf(wB0, xB0, aB.x); aB.x = fmaf(wB1, xB1, aB.x);
    aB.y = fmaf(wB0, yB0, aB.y); aB.y = fmaf(wB1, yB1, aB.y);
  }
  if (i < cm) {
    const int jA = (i < c0) ? i : 0;
    const int jB = (i < c1) ? i : 0;
    const int sA = csr_src[s0 + jA];
    const int sB = csr_src[s1 + jB];
    const half2v vA = *(const half2v*)(h + (size_t)sA * 128 + lane * 2);
    const half2v vB = *(const half2v*)(h + (size_t)sB * 128 + lane * 2);
    const float xA2 = (float)vA[0], yA2 = (float)vA[1];
    const float xB2 = (float)vB[0], yB2 = (float)vB[1];
    float tA = fmaf(xA2, asv.x, yA2 * asv.y);
    float tB = fmaf(xB2, asv.x, yB2 * asv.y);
#pragma unroll
    for (int off = 1; off < 64; off <<= 1) {
      tA += __shfl_xor(tA, off);
      tB += __shfl_xor(tB, off);
    }
    float eA2 = tA + adA, eB2 = tB + adB;
    eA2 = (eA2 > 0.f) ? eA2 : kNegSlope * eA2;
    eB2 = (eB2 > 0.f) ? eB2 : kNegSlope * eB2;
    const float wA = (i < c0) ? fexp(eA2) : 0.f;
    const float wB = (i < c1) ? fexp(eB2) : 0.f;
    dA += wA;
    dB += wB;
    aA.x = fmaf(wA, xA2, aA.x);
    aA.y = fmaf(wA, yA2, aA.y);
    aB.x = fmaf(wB, xB2, aB.x);
    aB.y = fmaf(wB, yB2, aB.y);
  }
  const float invA = 1.f / (dA + 1e-16f);
  const float invB = 1.f / (dB + 1e-16f);
  *(float2*)(out + (size_t)n0 * 128 + lane * 2) =
      make_float2(aA.x * invA + bias[lane * 2],
                  aA.y * invA + bias[lane * 2 + 1]);
  if (has1)
    *(float2*)(out + (size_t)n1r * 128 + lane * 2) =
        make_float2(aB.x * invB + bias[lane * 2],
                    aB.y * invB + bias[lane * 2 + 1]);
}

// ------- global max pool over sorted batch (both encoders, 1 launch) ---
__global__ void pool_max2(const float* __restrict__ x, const int* __restrict__ bt1,
                          const int* __restrict__ bt2, float* __restrict__ emb) {
  __shared__ int lohi[2];
  const int enc = blockIdx.x >> 8;
  const int g = blockIdx.x & 255;
  const int* batch = enc ? bt2 : bt1;
  const float* xx = x + (size_t)enc * kN * 128;
  if (threadIdx.x == 0) {
    int lo = 0, hi = kN;
    while (lo < hi) {
      const int mid = (lo + hi) >> 1;
      if (batch[mid] < g) lo = mid + 1; else hi = mid;
    }
    lohi[0] = lo;
    hi = kN;
    while (lo < hi) {
      const int mid = (lo + hi) >> 1;
      if (batch[mid] < g + 1) lo = mid + 1; else hi = mid;
    }
    lohi[1] = lo;
  }
  __syncthreads();
  const int lo = lohi[0], hi = lohi[1];
  const int c = threadIdx.x;  // 128 channels
  float m = -1e30f;
  for (int nid = lo; nid < hi; ++nid) m = fmaxf(m, xx[(size_t)nid * 128 + c]);
  emb[(size_t)blockIdx.x * 128 + c] = (lo < hi) ? m : 0.f;
}
// ------- single-encoder pool (fallback path) --------------------------
__global__ void pool_max(const float* __restrict__ x, const int* __restrict__ batch,
                         float* __restrict__ emb, int n_nodes) {
  __shared__ int lohi[2];
  const int g = blockIdx.x;
  if (threadIdx.x == 0) {
    int lo = 0, hi = n_nodes;
    while (lo < hi) {
      const int mid = (lo + hi) >> 1;
      if (batch[mid] < g) lo = mid + 1; else hi = mid;
    }
    lohi[0] = lo;
    hi = n_nodes;
    while (lo < hi) {
      const int mid = (lo + hi) >> 1;
      if (batch[mid] < g + 1) lo = mid + 1; else hi = mid;
    }
    lohi[1] = lo;
  }
  __syncthreads();
  const int lo = lohi[0], hi = lohi[1];
  const int c = threadIdx.x;  // 128 channels
  float m = -1e30f;
  for (int nid = lo; nid < hi; ++nid) m = fmaxf(m, x[(size_t)nid * 128 + c]);
  emb[g * 128 + c] = (lo < hi) ? m : 0.f;
}

// ---------------- final MLP head --------------------------------------
__global__ void mlp_head(const float* __restrict__ e1, const float* __restrict__ e2,
                         const float* __restrict__ mw1, const float* __restrict__ mb1,
                         const float* __restrict__ mw2, const float* __restrict__ mb2,
                         float* __restrict__ out) {
  __shared__ float z[256];
  __shared__ float red[128];
  const int g = blockIdx.x;
  const int j = threadIdx.x;  // 128
  z[j] = e1[g * 128 + j];
  z[j + 128] = e2[g * 128 + j];
  __syncthreads();
  float acc = mb1[j];
  for (int k = 0; k < 256; ++k) acc = fmaf(z[k], mw1[k * 128 + j], acc);
  acc = fmaxf(acc, 0.f) * mw2[j];
  red[j] = acc;
  __syncthreads();
  for (int s = 64; s > 0; s >>= 1) {
    if (j < s) red[j] += red[j + s];
    __syncthreads();
  }
  if (j == 0) out[g] = red[0] + mb2[0];
}

// ---------------- launcher --------------------------------------------
namespace {
struct Bufs {
  _Float16 *R1h, *R2h;
  float *R1f, *R2f, *asrc, *adst;
  int *cnt, *start, *cursor, *csr, *total;
  _Float16 *Wth1, *Wth2, *Wth3;
  float* emb;
  size_t need;
};

Bufs plan(void* d_ws, int M, int E) {
  Bufs b;
  char* w = (char*)d_ws;
  size_t off = 0;
  auto take = [&](size_t bytes) -> void* {
    void* p = w + off;
    off += (bytes + 255) & ~(size_t)255;
    return p;
  };
  b.R1h = (_Float16*)take((size_t)M * 512 * 2);  // f16 activations
  b.R1f = (float*)b.R1h;                         // layer-3 out alias [M,128]
  b.R2h = (_Float16*)take((size_t)M * 512 * 2);  // h f16 (l3 h f16 [M,128])
  b.R2f = (float*)b.R2h;
  b.asrc = (float*)take((size_t)M * 4 * 4);      // (kept for ws layout stability)
  b.adst = (float*)take((size_t)M * 4 * 4);
  b.cnt = (int*)take((size_t)M * 4);
  b.start = (int*)take((size_t)M * 4);
  b.cursor = (int*)take((size_t)M * 4);
  b.csr = (int*)take((size_t)E * 4);
  b.total = (int*)take(256);
  b.Wth1 = (_Float16*)take((size_t)64 * 512 * 2);
  b.Wth2 = (_Float16*)take((size_t)512 * 512 * 2);
  b.Wth3 = (_Float16*)take((size_t)512 * 128 * 2);
  b.emb = (float*)take((size_t)2 * kG * 128 * 4);
  b.need = off;
  return b;
}

void run_layers(const Bufs& b, void* const* d_in, int M, hipStream_t stream) {
  const float* as1 = (const float*)d_in[7];
  const float* ad1 = (const float*)d_in[8];
  const float* b1 = (const float*)d_in[9];
  const float* as2 = (const float*)d_in[11];
  const float* ad2 = (const float*)d_in[12];
  const float* b2 = (const float*)d_in[13];
  const float* as3 = (const float*)d_in[15];
  const float* ad3 = (const float*)d_in[16];
  const float* b3 = (const float*)d_in[17];
  const int aggBlocks = (((M + 1) / 2) * 64 + 255) / 256;  // 2 nodes/wave
  const int RT = (M + 127) / 128;         // 128-row tiles
  const int SP = (RT + 7) / 8;            // row-tile groups of 8 (XCD map)

  // layer 1: [M,64] @ [64,512], h -> f16 (A1h aliases R1h)
  gemm_ring<1, 256, 2><<<SP * 16, 256, 0, stream>>>(b.R1h, b.Wth1, b.R2h, M, 512, 64);
  gat_agg4<<<aggBlocks, 256, 0, stream>>>(b.R2h, as1, ad1, b.start, b.cnt,
                                          b.csr, b1, b.R1h, M);
  // layer 2: [M,512] @ [512,512], h -> f16
  gemm_ring<1, 256, 2><<<SP * 16, 256, 0, stream>>>(b.R1h, b.Wth2, b.R2h, M, 512, 512);
  gat_agg4<<<aggBlocks, 256, 0, stream>>>(b.R2h, as2, ad2, b.start, b.cnt,
                                          b.csr, b2, b.R1h, M);
  // layer 3: [M,512] @ [512,128], H=1, no elu, h -> f16
  gemm_ring<1, 128, 1><<<SP * 8, 256, 0, stream>>>(b.R1h, b.Wth3, b.R2h, M, 128, 512);
  gat_agg_l3<<<aggBlocks, 256, 0, stream>>>(b.R2h, as3, ad3, b.start, b.cnt,
                                            b.csr, b3, b.R1f, M);
}
}  // namespace

extern "C" void kernel_launch(void* const* d_in, const int* in_sizes, int n_in,
                              void* d_out, int out_size, void* d_ws, size_t ws_size,
                              hipStream_t stream) {
  (void)in_sizes; (void)n_in; (void)out_size;
  const float* W1 = (const float*)d_in[6];
  const float* W2 = (const float*)d_in[10];
  const float* W3 = (const float*)d_in[14];
  const float* mw1 = (const float*)d_in[18];
  const float* mb1 = (const float*)d_in[19];
  const float* mw2 = (const float*)d_in[20];
  const float* mb2 = (const float*)d_in[21];

  // Prefer combined (both encoders batched, M=2N) if it fits the workspace.
  Bufs bc = plan(d_ws, 2 * kN, 2 * kE2);
  const bool combined = bc.need <= ws_size;
  Bufs b = combined ? bc : plan(d_ws, kN, kE2);

  const int wtot = 64 * 512 + 512 * 512 + 512 * 128;
  if (combined) {
    const int M = 2 * kN;
    const int* ei0 = (const int*)d_in[1];
    const int* ei1 = (const int*)d_in[4];
    prep_all<<<(M * 64 + wtot + 255) / 256, 256, 0, stream>>>(
        (const float*)d_in[0], (const float*)d_in[3], b.R1h, b.cnt, b.total,
        W1, b.Wth1, W2, b.Wth2, W3, b.Wth3);
    count_edges2<<<(2 * kE + 255) / 256, 256, 0, stream>>>(ei0 + kE, ei1 + kE,
                                                           b.cnt);
    alloc_ranges<<<(M + 255) / 256, 256, 0, stream>>>(b.cnt, b.start, b.cursor,
                                                      b.total, b.csr, M);
    fill_edges2<<<(2 * kE + 255) / 256, 256, 0, stream>>>(ei0, ei0 + kE, ei1,
                                                          ei1 + kE, b.cursor, b.csr);
    run_layers(b, d_in, M, stream);
    pool_max2<<<2 * kG, 128, 0, stream>>>(b.R1f, (const int*)d_in[2],
                                          (const int*)d_in[5], b.emb);
  } else {
    wt_split_all<<<(wtot + 255) / 256, 256, 0, stream>>>(W1, b.Wth1, W2, b.Wth2,
                                                         W3, b.Wth3);
    for (int enc = 0; enc < 2; ++enc) {
      const float* x = (const float*)d_in[enc * 3 + 0];
      const int* ei = (const int*)d_in[enc * 3 + 1];
      const int* batch = (const int*)d_in[enc * 3 + 2];
      prep<<<(kN * 64 + 255) / 256, 256, 0, stream>>>(x, b.R1h, b.cnt, b.total,
                                                      kN * 64, kN);
      count_edges<<<(kE + 255) / 256, 256, 0, stream>>>(ei + kE, b.cnt, kE);
      alloc_ranges<<<(kN + 255) / 256, 256, 0, stream>>>(b.cnt, b.start, b.cursor,
                                                         b.total, b.csr, kN);
      fill_edges<<<(kE + 255) / 256, 256, 0, stream>>>(ei, ei + kE, b.cursor, b.csr,
                                                       kE);
      run_layers(b, d_in, kN, stream);
      pool_max<<<kG, 128, 0, stream>>>(b.R1f, batch, b.emb + (size_t)enc * kG * 128,
                                       kN);
    }
  }
  mlp_head<<<kG, 128, 0, stream>>>(b.emb, b.emb + (size_t)kG * 128, mw1, mb1, mw2,
                                   mb2, (float*)d_out);
}